// Round 7
// baseline (12788.475 us; speedup 1.0000x reference)
//
#include <hip/hip_runtime.h>
#include <math.h>

// ---------------- problem constants ----------------
#define CB 8
#define CT 16
#define CN 256
#define CD 1280
#define CH 512
#define CS 3
#define CM (CB*CT*CN)      // 32768 rows
#define CBS (CB*CS)        // 24
#define CH3 (3*CH)         // 1536
#define CH2 (2*CH)         // 1024
#define NITER 3

// ---------------- workspace layout (float offsets) ----------------
#define OFS_P1   0ULL                       // P1, later feats (in-place): CM*CH
#define OFS_M1   16777216ULL                // M1, later k_buf (overwrite): CM*CH
#define OFS_V    33554432ULL                // v buf (row-major): CM*CH
#define OFS_ST   50331648ULL                // rowstats: CM*2
#define OFS_WQT  50397184ULL                // wqT  [k=512][512]
#define OFS_WHHT (OFS_WQT + 262144ULL)      // whhT [k=512][1536]
#define OFS_WIHT (OFS_WHHT + 786432ULL)     // wihT [k=512][1536]
#define OFS_WM1T (OFS_WIHT + 786432ULL)     // wm1T [k=512][1024]
#define OFS_WM2T (OFS_WM1T + 524288ULL)     // wm2T [k=1024][512]
#define OFS_WTOT (OFS_WM2T + 524288ULL)     // stage-3 transposes
#define OFS_WTQT (OFS_WTOT + 262144ULL)
#define OFS_WTKT (OFS_WTQT + 262144ULL)
#define OFS_WTVT (OFS_WTKT + 262144ULL)
#define OFS_SLOTS (OFS_WTVT + 262144ULL)    // 24*512
#define OFS_Q    (OFS_SLOTS + 12288ULL)     // 24*512
#define OFS_GH   (OFS_Q + 12288ULL)         // 24*1536
#define OFS_ATTN (OFS_GH + 36864ULL)        // (unused now)
#define OFS_U    (OFS_ATTN + 6144ULL)       // 24*512
#define OFS_Z    (OFS_U + 12288ULL)         // (unused)
#define OFS_H    (OFS_Z + 32ULL)            // 24*512
#define OFS_Y    (OFS_H + 12288ULL)         // 24*1024
#define OFS_TQKV (OFS_Y + 24576ULL)         // 384*1536
#define OFS_TO   (OFS_TQKV + 589824ULL)     // 384*512

// ---------------- GEMM tiling ----------------
#define BM 128
#define BN 128
#define BK 8

// ================= init: slots0, zero agg =================
__global__ __launch_bounds__(256) void k_init(const float* __restrict__ noise,
                                              const float* __restrict__ mu,
                                              const float* __restrict__ sigma,
                                              float* __restrict__ ws,
                                              float* __restrict__ out) {
  int i = blockIdx.x * 256 + threadIdx.x;
  if (i < 12288) {
    int sj = i % 1536;  // (s,h) index into mu/sigma [1,3,512]
    ws[OFS_SLOTS + i] = mu[sj] + sigma[sj] * noise[i];
    out[i] = 0.0f;      // zero slots_agg accumulation region
  }
}

// ================= weight transposes (k-major) =================
__global__ __launch_bounds__(256) void k_transpose(const float* __restrict__ w_q,
                                                   const float* __restrict__ w_hh,
                                                   const float* __restrict__ w_ih,
                                                   const float* __restrict__ w_mlp1,
                                                   const float* __restrict__ w_mlp2,
                                                   const float* __restrict__ w_to,
                                                   const float* __restrict__ w_tq,
                                                   const float* __restrict__ w_tk,
                                                   const float* __restrict__ w_tv,
                                                   float* __restrict__ ws) {
  const float* src; float* dst; int R, C;
  switch (blockIdx.z) {
    case 0: src = w_q;    dst = ws + OFS_WQT;  R = 512;  C = 512;  break;
    case 1: src = w_hh;   dst = ws + OFS_WHHT; R = 1536; C = 512;  break;
    case 2: src = w_ih;   dst = ws + OFS_WIHT; R = 1536; C = 512;  break;
    case 3: src = w_mlp1; dst = ws + OFS_WM1T; R = 1024; C = 512;  break;
    case 4: src = w_mlp2; dst = ws + OFS_WM2T; R = 512;  C = 1024; break;
    case 5: src = w_to;   dst = ws + OFS_WTOT; R = 512;  C = 512;  break;
    case 6: src = w_tq;   dst = ws + OFS_WTQT; R = 512;  C = 512;  break;
    case 7: src = w_tk;   dst = ws + OFS_WTKT; R = 512;  C = 512;  break;
    default: src = w_tv;  dst = ws + OFS_WTVT; R = 512;  C = 512;  break;
  }
  int r0 = blockIdx.y * 32, c0 = blockIdx.x * 32;
  if (r0 >= R || c0 >= C) return;
  __shared__ float tile[32][33];
  int tx = threadIdx.x & 31, ty = threadIdx.x >> 5;  // 32 x 8
  for (int i = ty; i < 32; i += 8)
    tile[i][tx] = src[(size_t)(r0 + i) * C + c0 + tx];
  __syncthreads();
  // dst[c*R + r] = src[r*C + c]  -> dst is [in_dim k][out_col]
  for (int i = ty; i < 32; i += 8)
    dst[(size_t)(c0 + i) * R + r0 + tx] = tile[tx][i];
}

// ================= GEMM 1: P1 = visual @ w_in.T + b_in =================
__global__ __launch_bounds__(256) void k_p1(const float* __restrict__ A,
                                            const float* __restrict__ W,
                                            const float* __restrict__ bias,
                                            float* __restrict__ Cout) {
  __shared__ float As[BK][BM + 4];
  __shared__ float Bs[BK][BN + 4];
  const int tid = threadIdx.x;
  const int m0 = blockIdx.y * BM;
  const int n0 = blockIdx.x * BN;
  const int tx = tid & 15, ty = tid >> 4;
  float acc[8][8];
#pragma unroll
  for (int i = 0; i < 8; ++i)
#pragma unroll
    for (int j = 0; j < 8; ++j) acc[i][j] = 0.f;

  for (int kb = 0; kb < CD; kb += BK) {
#pragma unroll
    for (int p = 0; p < 4; ++p) {
      int r = (tid >> 3) + p * 32;
      int k = tid & 7;
      As[k][r] = A[(size_t)(m0 + r) * CD + kb + k];
      Bs[k][r] = W[(size_t)(n0 + r) * CD + kb + k];
    }
    __syncthreads();
#pragma unroll
    for (int kk = 0; kk < BK; ++kk) {
      float av[8], bv[8];
      *(float4*)&av[0] = *(const float4*)&As[kk][ty * 8];
      *(float4*)&av[4] = *(const float4*)&As[kk][ty * 8 + 4];
      *(float4*)&bv[0] = *(const float4*)&Bs[kk][tx * 8];
      *(float4*)&bv[4] = *(const float4*)&Bs[kk][tx * 8 + 4];
#pragma unroll
      for (int i = 0; i < 8; ++i)
#pragma unroll
        for (int j = 0; j < 8; ++j) acc[i][j] += av[i] * bv[j];
    }
    __syncthreads();
  }
#pragma unroll
  for (int i = 0; i < 8; ++i) {
    int m = m0 + ty * 8 + i;
#pragma unroll
    for (int j = 0; j < 8; ++j) {
      int n = n0 + tx * 8 + j;
      Cout[(size_t)m * CH + n] = acc[i][j] + bias[n];
    }
  }
}

// ================= GEMM 2: M1 = relu(motion @ w_m1p.T + b_m1p) =================
__global__ __launch_bounds__(256) void k_m1(const float* __restrict__ A,
                                            const float* __restrict__ W,
                                            const float* __restrict__ bias,
                                            float* __restrict__ Cout) {
  __shared__ float As[BK][BM + 4];
  __shared__ float Bs[BK][BN + 4];
  const int tid = threadIdx.x;
  const int m0 = blockIdx.y * BM;
  const int n0 = blockIdx.x * BN;
  const int tx = tid & 15, ty = tid >> 4;
  const int frame = (m0 >> 8);         // (b*16 + t)
  const int tfrm = frame & 15;
  float acc[8][8];
#pragma unroll
  for (int i = 0; i < 8; ++i)
#pragma unroll
    for (int j = 0; j < 8; ++j) acc[i][j] = 0.f;

  for (int kb = 0; kb < CD; kb += BK) {
#pragma unroll
    for (int p = 0; p < 4; ++p) {
      int r = (tid >> 3) + p * 32;
      int k = tid & 7;
      float mv = 0.f;
      if (tfrm < 15) {
        float cur = A[(size_t)(m0 + r) * CD + kb + k];
        float nxt = A[(size_t)(m0 + r + 256) * CD + kb + k];
        mv = nxt - cur;
      }
      As[k][r] = mv;
      Bs[k][r] = W[(size_t)(n0 + r) * CD + kb + k];
    }
    __syncthreads();
#pragma unroll
    for (int kk = 0; kk < BK; ++kk) {
      float av[8], bv[8];
      *(float4*)&av[0] = *(const float4*)&As[kk][ty * 8];
      *(float4*)&av[4] = *(const float4*)&As[kk][ty * 8 + 4];
      *(float4*)&bv[0] = *(const float4*)&Bs[kk][tx * 8];
      *(float4*)&bv[4] = *(const float4*)&Bs[kk][tx * 8 + 4];
#pragma unroll
      for (int i = 0; i < 8; ++i)
#pragma unroll
        for (int j = 0; j < 8; ++j) acc[i][j] += av[i] * bv[j];
    }
    __syncthreads();
  }
#pragma unroll
  for (int i = 0; i < 8; ++i) {
    int m = m0 + ty * 8 + i;
#pragma unroll
    for (int j = 0; j < 8; ++j) {
      int n = n0 + tx * 8 + j;
      Cout[(size_t)m * CH + n] = fmaxf(acc[i][j] + bias[n], 0.f);
    }
  }
}

// ================= row stats of P1 for LN =================
__global__ __launch_bounds__(256) void k_rowstats(const float* __restrict__ P1,
                                                  float* __restrict__ st) {
  int row = blockIdx.x * 4 + (threadIdx.x >> 6);
  int lane = threadIdx.x & 63;
  const float* r = P1 + (size_t)row * CH;
  float4 x0 = *(const float4*)&r[lane * 8];
  float4 x1 = *(const float4*)&r[lane * 8 + 4];
  float s = x0.x + x0.y + x0.z + x0.w + x1.x + x1.y + x1.z + x1.w;
  for (int o = 32; o; o >>= 1) s += __shfl_xor(s, o);
  float mean = s * (1.f / CH);
  float d, s2 = 0.f;
  d = x0.x - mean; s2 += d * d; d = x0.y - mean; s2 += d * d;
  d = x0.z - mean; s2 += d * d; d = x0.w - mean; s2 += d * d;
  d = x1.x - mean; s2 += d * d; d = x1.y - mean; s2 += d * d;
  d = x1.z - mean; s2 += d * d; d = x1.w - mean; s2 += d * d;
  for (int o = 32; o; o >>= 1) s2 += __shfl_xor(s2, o);
  if (lane == 0) {
    st[2 * row] = mean;
    st[2 * row + 1] = rsqrtf(s2 * (1.f / CH) + 1e-5f);
  }
}

// ================= GEMM 3: feats = LN(P1)*g+b + 0.5*(M1 @ w_m2p.T + b_m2p), in-place =================
__global__ __launch_bounds__(256) void k_feats(const float* __restrict__ A,  // M1
                                               const float* __restrict__ W,  // w_m2p
                                               const float* __restrict__ bias,
                                               const float* __restrict__ st,
                                               const float* __restrict__ g_ln,
                                               const float* __restrict__ b_ln,
                                               float* __restrict__ P1inout) {
  __shared__ float As[BK][BM + 4];
  __shared__ float Bs[BK][BN + 4];
  const int tid = threadIdx.x;
  const int m0 = blockIdx.y * BM;
  const int n0 = blockIdx.x * BN;
  const int tx = tid & 15, ty = tid >> 4;
  float acc[8][8];
#pragma unroll
  for (int i = 0; i < 8; ++i)
#pragma unroll
    for (int j = 0; j < 8; ++j) acc[i][j] = 0.f;

  for (int kb = 0; kb < CH; kb += BK) {
#pragma unroll
    for (int p = 0; p < 4; ++p) {
      int r = (tid >> 3) + p * 32;
      int k = tid & 7;
      As[k][r] = A[(size_t)(m0 + r) * CH + kb + k];
      Bs[k][r] = W[(size_t)(n0 + r) * CH + kb + k];
    }
    __syncthreads();
#pragma unroll
    for (int kk = 0; kk < BK; ++kk) {
      float av[8], bv[8];
      *(float4*)&av[0] = *(const float4*)&As[kk][ty * 8];
      *(float4*)&av[4] = *(const float4*)&As[kk][ty * 8 + 4];
      *(float4*)&bv[0] = *(const float4*)&Bs[kk][tx * 8];
      *(float4*)&bv[4] = *(const float4*)&Bs[kk][tx * 8 + 4];
#pragma unroll
      for (int i = 0; i < 8; ++i)
#pragma unroll
        for (int j = 0; j < 8; ++j) acc[i][j] += av[i] * bv[j];
    }
    __syncthreads();
  }
#pragma unroll
  for (int i = 0; i < 8; ++i) {
    int m = m0 + ty * 8 + i;
    float mean = st[2 * m], rstd = st[2 * m + 1];
#pragma unroll
    for (int j = 0; j < 8; ++j) {
      int n = n0 + tx * 8 + j;
      size_t idx = (size_t)m * CH + n;
      float p1v = P1inout[idx];
      float v = (p1v - mean) * rstd * g_ln[n] + b_ln[n] + 0.5f * (acc[i][j] + bias[n]);
      P1inout[idx] = v;
    }
  }
}

// ================= GEMM 4: k | v (both row-major) = feats @ [w_k; w_v].T =================
__global__ __launch_bounds__(256) void k_kv(const float* __restrict__ A,  // feats
                                            const float* __restrict__ Wk,
                                            const float* __restrict__ Wv,
                                            float* __restrict__ kbuf,
                                            float* __restrict__ vbuf) {
  __shared__ float As[BK][BM + 4];
  __shared__ float Bs[BK][BN + 4];
  const int tid = threadIdx.x;
  const int m0 = blockIdx.y * BM;
  const int n0 = blockIdx.x * BN;  // 0..1023
  const int tx = tid & 15, ty = tid >> 4;
  const bool khalf = (n0 < 512);
  const float* W = khalf ? (Wk + (size_t)n0 * CH) : (Wv + (size_t)(n0 - 512) * CH);
  float* Out = khalf ? kbuf : vbuf;
  const int nbase = khalf ? n0 : (n0 - 512);
  float acc[8][8];
#pragma unroll
  for (int i = 0; i < 8; ++i)
#pragma unroll
    for (int j = 0; j < 8; ++j) acc[i][j] = 0.f;

  for (int kb = 0; kb < CH; kb += BK) {
#pragma unroll
    for (int p = 0; p < 4; ++p) {
      int r = (tid >> 3) + p * 32;
      int k = tid & 7;
      As[k][r] = A[(size_t)(m0 + r) * CH + kb + k];
      Bs[k][r] = W[(size_t)r * CH + kb + k];
    }
    __syncthreads();
#pragma unroll
    for (int kk = 0; kk < BK; ++kk) {
      float av[8], bv[8];
      *(float4*)&av[0] = *(const float4*)&As[kk][ty * 8];
      *(float4*)&av[4] = *(const float4*)&As[kk][ty * 8 + 4];
      *(float4*)&bv[0] = *(const float4*)&Bs[kk][tx * 8];
      *(float4*)&bv[4] = *(const float4*)&Bs[kk][tx * 8 + 4];
#pragma unroll
      for (int i = 0; i < 8; ++i)
#pragma unroll
        for (int j = 0; j < 8; ++j) acc[i][j] += av[i] * bv[j];
    }
    __syncthreads();
  }
#pragma unroll
  for (int i = 0; i < 8; ++i) {
    int m = m0 + ty * 8 + i;
#pragma unroll
    for (int j = 0; j < 8; ++j) {
      int n = nbase + tx * 8 + j;
      Out[(size_t)m * CH + n] = acc[i][j];
    }
  }
}

// ============================================================================
// Slot-attention scan, phase-split v2: each block owns a COLUMN slice for ALL
// 24 rows (activations staged in LDS, each weight column read exactly once).
// Round-6 post-mortem: row-sliced grids re-read weights 24x -> ~13 GB L3
// traffic; this layout cuts it to ~0.55 GB. 5 kernels/iter = 240 graph nodes.
// ============================================================================

// ---- Phase A: q = LN(slots)@wqT (blocks 0..7), gh = slots@whhT + b_hh (8..31) ----
__global__ __launch_bounds__(256) void ph_A(float* __restrict__ ws,
                                            const float* __restrict__ g_ls,
                                            const float* __restrict__ b_ls,
                                            const float* __restrict__ b_hh) {
  __shared__ float sb[CBS * CH];     // 48 KB: raw slots, normalized in place for q-blocks
  __shared__ float lm[CBS], lr[CBS];
  const int bx = blockIdx.x;         // 0..31 -> 64 cols of [q(512)|gh(1536)]
  const int tid = threadIdx.x;
  const float* slots = ws + OFS_SLOTS;
  for (int i = tid; i < CBS * CH / 4; i += 256)
    ((float4*)sb)[i] = ((const float4*)slots)[i];
  __syncthreads();
  if (bx < 8) {                      // q-blocks: LN in place
    int wv = tid >> 6, lane = tid & 63;
    for (int rr = 0; rr < 6; ++rr) {
      int r = wv * 6 + rr;
      const float* row = sb + r * CH;
      float s = 0.f;
#pragma unroll
      for (int i = 0; i < 8; ++i) s += row[lane + 64 * i];
      for (int o = 32; o; o >>= 1) s += __shfl_xor(s, o);
      float mean = s * (1.f / CH);
      float s2 = 0.f;
#pragma unroll
      for (int i = 0; i < 8; ++i) { float d = row[lane + 64 * i] - mean; s2 += d * d; }
      for (int o = 32; o; o >>= 1) s2 += __shfl_xor(s2, o);
      if (lane == 0) { lm[r] = mean; lr[r] = rsqrtf(s2 * (1.f / CH) + 1e-5f); }
    }
    __syncthreads();
    for (int i = tid; i < CBS * CH; i += 256) {
      int r = i >> 9, k = i & 511;
      sb[i] = (sb[i] - lm[r]) * lr[r] * g_ls[k] + b_ls[k];
    }
    __syncthreads();
  }
  const int cl = tid & 63, rg = tid >> 6;   // rows rg*6..+6
  const int c = bx * 64 + cl;
  float a0 = 0.f, a1 = 0.f, a2 = 0.f, a3 = 0.f, a4 = 0.f, a5 = 0.f;
  const float* src = sb + rg * 6 * CH;
  if (c < CH) {
    const float* w = ws + OFS_WQT + c;
#pragma unroll 4
    for (int k = 0; k < CH; ++k) {
      float wv_ = w[(size_t)k * CH];
      a0 += src[k] * wv_;          a1 += src[CH + k] * wv_;
      a2 += src[2 * CH + k] * wv_; a3 += src[3 * CH + k] * wv_;
      a4 += src[4 * CH + k] * wv_; a5 += src[5 * CH + k] * wv_;
    }
    float* q = ws + OFS_Q;
    q[(rg * 6 + 0) * CH + c] = a0; q[(rg * 6 + 1) * CH + c] = a1;
    q[(rg * 6 + 2) * CH + c] = a2; q[(rg * 6 + 3) * CH + c] = a3;
    q[(rg * 6 + 4) * CH + c] = a4; q[(rg * 6 + 5) * CH + c] = a5;
  } else {
    const int cg = c - CH;
    const float* w = ws + OFS_WHHT + cg;
#pragma unroll 4
    for (int k = 0; k < CH; ++k) {
      float wv_ = w[(size_t)k * CH3];
      a0 += src[k] * wv_;          a1 += src[CH + k] * wv_;
      a2 += src[2 * CH + k] * wv_; a3 += src[3 * CH + k] * wv_;
      a4 += src[4 * CH + k] * wv_; a5 += src[5 * CH + k] * wv_;
    }
    float bb = b_hh[cg];
    float* gh = ws + OFS_GH;
    gh[(rg * 6 + 0) * CH3 + cg] = a0 + bb; gh[(rg * 6 + 1) * CH3 + cg] = a1 + bb;
    gh[(rg * 6 + 2) * CH3 + cg] = a2 + bb; gh[(rg * 6 + 3) * CH3 + cg] = a3 + bb;
    gh[(rg * 6 + 4) * CH3 + cg] = a4 + bb; gh[(rg * 6 + 5) * CH3 + cg] = a5 + bb;
  }
}

// ---- Phase B: attn (softmax over s) + U = (attn@v)/Z. grid (2 cs, 8 b) ----
__global__ __launch_bounds__(256) void ph_B(float* __restrict__ ws,
                                            float* __restrict__ att,
                                            int t, int lastit) {
  const int cs = blockIdx.x, b = blockIdx.y;
  const int tid = threadIdx.x, wv = tid >> 6, lane = tid & 63;
  __shared__ float q3[3 * CH];       // 6 KB
  __shared__ float at[3 * CN];       // 3 KB
  __shared__ float izl[3];
  const float* qb = ws + OFS_Q + (size_t)b * 3 * CH;
  for (int i = tid; i < 3 * CH / 4; i += 256)
    ((float4*)q3)[i] = ((const float4*)qb)[i];
  __syncthreads();
  const float* kbuf = ws + OFS_M1 + ((size_t)(b * CT + t) * CN) * CH;
  const float scale = 0.04419417382415922f;  // 512^-0.5
  for (int i = 0; i < 64; ++i) {
    int n = wv * 64 + i;
    const float* krow = kbuf + (size_t)n * CH;
    float p0 = 0.f, p1 = 0.f, p2 = 0.f;
#pragma unroll
    for (int u = 0; u < 2; ++u) {
      int k = lane * 8 + u * 4;
      float4 kk = *(const float4*)&krow[k];
      float4 b0 = *(const float4*)&q3[k];
      float4 b1 = *(const float4*)&q3[CH + k];
      float4 b2 = *(const float4*)&q3[2 * CH + k];
      p0 += b0.x * kk.x + b0.y * kk.y + b0.z * kk.z + b0.w * kk.w;
      p1 += b1.x * kk.x + b1.y * kk.y + b1.z * kk.z + b1.w * kk.w;
      p2 += b2.x * kk.x + b2.y * kk.y + b2.z * kk.z + b2.w * kk.w;
    }
    for (int o = 32; o; o >>= 1) {
      p0 += __shfl_xor(p0, o); p1 += __shfl_xor(p1, o); p2 += __shfl_xor(p2, o);
    }
    p0 *= scale; p1 *= scale; p2 *= scale;
    float mx = fmaxf(p0, fmaxf(p1, p2));
    float e0 = expf(p0 - mx), e1 = expf(p1 - mx), e2 = expf(p2 - mx);
    float inv = 1.f / (e0 + e1 + e2);
    if (lane < 3) {
      float a = (lane == 0 ? e0 : (lane == 1 ? e1 : e2)) * inv;
      at[lane * CN + n] = a;
      if (lastit && cs == 0)
        att[((size_t)(b * CT + t) * CS + lane) * CN + n] = a;
    }
  }
  __syncthreads();
  if (wv < 3) {  // Z per slot
    const float* arow = at + wv * CN;
    float z = arow[lane] + arow[lane + 64] + arow[lane + 128] + arow[lane + 192];
    for (int o = 32; o; o >>= 1) z += __shfl_xor(z, o);
    if (lane == 0) izl[wv] = 1.f / (z + 1e-8f);
  }
  __syncthreads();
  const int c = cs * 256 + tid;
  const float* v = ws + OFS_V + ((size_t)(b * CT + t) * CN) * CH + c;
  float u0 = 0.f, u1 = 0.f, u2 = 0.f;
#pragma unroll 4
  for (int n = 0; n < CN; ++n) {
    float vv = v[(size_t)n * CH];
    u0 += at[n] * vv; u1 += at[CN + n] * vv; u2 += at[2 * CN + n] * vv;
  }
  float* U = ws + OFS_U + (size_t)b * 3 * CH;
  U[c] = u0 * izl[0]; U[CH + c] = u1 * izl[1]; U[2 * CH + c] = u2 * izl[2];
}

// ---- Phase C: gi = U@wihT + b_ih (3 gates x 32 j per block) ; GRU -> h. grid 16 ----
__global__ __launch_bounds__(256) void ph_C(float* __restrict__ ws,
                                            const float* __restrict__ b_ih) {
  __shared__ float Ul[CBS * CH];         // 48 KB
  __shared__ float gil[CBS * 3 * 32];    // 9 KB
  const int bx = blockIdx.x;             // j0 = bx*32
  const int tid = threadIdx.x;
  const int j0 = bx * 32;
  const float* U = ws + OFS_U;
  for (int i = tid; i < CBS * CH / 4; i += 256)
    ((float4*)Ul)[i] = ((const float4*)U)[i];
  __syncthreads();
  if (tid < 192) {
    const int jl = tid & 31;
    const int g6 = tid >> 5;             // 0..5
    const int g = g6 % 3, rh = g6 / 3;   // rh: rows rh*12..+12
    const int col = g * 512 + j0 + jl;
    const float* w = ws + OFS_WIHT + col;
    const float* src = Ul + rh * 12 * CH;
    float a[12];
#pragma unroll
    for (int i = 0; i < 12; ++i) a[i] = 0.f;
#pragma unroll 4
    for (int k = 0; k < CH; ++k) {
      float wv_ = w[(size_t)k * CH3];
#pragma unroll
      for (int i = 0; i < 12; ++i) a[i] += src[i * CH + k] * wv_;
    }
    float bb = b_ih[col];
#pragma unroll
    for (int i = 0; i < 12; ++i) gil[((rh * 12 + i) * 3 + g) * 32 + jl] = a[i] + bb;
  }
  __syncthreads();
  {
    const int jl = tid & 31, rt = tid >> 5;  // rt 0..7 -> rows rt*3..+3
    const int j = j0 + jl;
    const float* gh = ws + OFS_GH;
    const float* slots = ws + OFS_SLOTS;
    float* hb = ws + OFS_H;
#pragma unroll
    for (int i = 0; i < 3; ++i) {
      int r = rt * 3 + i;
      float ir = gil[(r * 3 + 0) * 32 + jl];
      float iz = gil[(r * 3 + 1) * 32 + jl];
      float inn = gil[(r * 3 + 2) * 32 + jl];
      float hr = gh[(size_t)r * CH3 + j];
      float hz = gh[(size_t)r * CH3 + CH + j];
      float hn = gh[(size_t)r * CH3 + 2 * CH + j];
      float rr = 1.f / (1.f + expf(-(ir + hr)));
      float zz = 1.f / (1.f + expf(-(iz + hz)));
      float nn = tanhf(inn + rr * hn);
      hb[(size_t)r * CH + j] = (1.f - zz) * nn + zz * slots[(size_t)r * CH + j];
    }
  }
}

// ---- Phase D: y = gelu(LN(h)@wm1T + b_m1). grid 16 x 64 cols ----
__global__ __launch_bounds__(256) void ph_D(float* __restrict__ ws,
                                            const float* __restrict__ g_lm,
                                            const float* __restrict__ b_lm,
                                            const float* __restrict__ b_m1) {
  __shared__ float sb[CBS * CH];     // 48 KB (normalized in place)
  __shared__ float lm[CBS], lr[CBS];
  const int bx = blockIdx.x;         // 0..15 -> 64 cols of 1024
  const int tid = threadIdx.x;
  const float* hb = ws + OFS_H;
  for (int i = tid; i < CBS * CH / 4; i += 256)
    ((float4*)sb)[i] = ((const float4*)hb)[i];
  __syncthreads();
  {
    int wv = tid >> 6, lane = tid & 63;
    for (int rr = 0; rr < 6; ++rr) {
      int r = wv * 6 + rr;
      const float* row = sb + r * CH;
      float s = 0.f;
#pragma unroll
      for (int i = 0; i < 8; ++i) s += row[lane + 64 * i];
      for (int o = 32; o; o >>= 1) s += __shfl_xor(s, o);
      float mean = s * (1.f / CH);
      float s2 = 0.f;
#pragma unroll
      for (int i = 0; i < 8; ++i) { float d = row[lane + 64 * i] - mean; s2 += d * d; }
      for (int o = 32; o; o >>= 1) s2 += __shfl_xor(s2, o);
      if (lane == 0) { lm[r] = mean; lr[r] = rsqrtf(s2 * (1.f / CH) + 1e-5f); }
    }
  }
  __syncthreads();
  for (int i = tid; i < CBS * CH; i += 256) {
    int r = i >> 9, k = i & 511;
    sb[i] = (sb[i] - lm[r]) * lr[r] * g_lm[k] + b_lm[k];
  }
  __syncthreads();
  const int cl = tid & 63, rg = tid >> 6;
  const int c = bx * 64 + cl;
  const float* w = ws + OFS_WM1T + c;
  const float* src = sb + rg * 6 * CH;
  float a0 = 0.f, a1 = 0.f, a2 = 0.f, a3 = 0.f, a4 = 0.f, a5 = 0.f;
#pragma unroll 4
  for (int k = 0; k < CH; ++k) {
    float wv_ = w[(size_t)k * CH2];
    a0 += src[k] * wv_;          a1 += src[CH + k] * wv_;
    a2 += src[2 * CH + k] * wv_; a3 += src[3 * CH + k] * wv_;
    a4 += src[4 * CH + k] * wv_; a5 += src[5 * CH + k] * wv_;
  }
  float bb = b_m1[c];
  float* yb = ws + OFS_Y;
  float x;
  x = a0 + bb; yb[(rg * 6 + 0) * CH2 + c] = 0.5f * x * (1.f + erff(x * 0.70710678118654752f));
  x = a1 + bb; yb[(rg * 6 + 1) * CH2 + c] = 0.5f * x * (1.f + erff(x * 0.70710678118654752f));
  x = a2 + bb; yb[(rg * 6 + 2) * CH2 + c] = 0.5f * x * (1.f + erff(x * 0.70710678118654752f));
  x = a3 + bb; yb[(rg * 6 + 3) * CH2 + c] = 0.5f * x * (1.f + erff(x * 0.70710678118654752f));
  x = a4 + bb; yb[(rg * 6 + 4) * CH2 + c] = 0.5f * x * (1.f + erff(x * 0.70710678118654752f));
  x = a5 + bb; yb[(rg * 6 + 5) * CH2 + c] = 0.5f * x * (1.f + erff(x * 0.70710678118654752f));
}

// ---- Phase E: slots' = h + y@wm2T + b_m2. grid 8 x 64 cols ----
__global__ __launch_bounds__(256) void ph_E(float* __restrict__ ws,
                                            const float* __restrict__ b_m2,
                                            float* __restrict__ spf,
                                            int t, int lastit) {
  __shared__ float yl[CBS * CH2];    // 96 KB
  const int bx = blockIdx.x;         // 0..7 -> 64 cols of 512
  const int tid = threadIdx.x;
  const float* yb = ws + OFS_Y;
  for (int i = tid; i < CBS * CH2 / 4; i += 256)
    ((float4*)yl)[i] = ((const float4*)yb)[i];
  __syncthreads();
  const int cl = tid & 63, rg = tid >> 6;
  const int c = bx * 64 + cl;
  const float* w = ws + OFS_WM2T + c;
  const float* src = yl + rg * 6 * CH2;
  float a0 = 0.f, a1 = 0.f, a2 = 0.f, a3 = 0.f, a4 = 0.f, a5 = 0.f;
#pragma unroll 4
  for (int k = 0; k < CH2; ++k) {
    float wv_ = w[(size_t)k * CH];
    a0 += src[k] * wv_;           a1 += src[CH2 + k] * wv_;
    a2 += src[2 * CH2 + k] * wv_; a3 += src[3 * CH2 + k] * wv_;
    a4 += src[4 * CH2 + k] * wv_; a5 += src[5 * CH2 + k] * wv_;
  }
  const float* hb = ws + OFS_H;
  float* slots = ws + OFS_SLOTS;
  float bb = b_m2[c];
  float acc[6] = {a0, a1, a2, a3, a4, a5};
#pragma unroll
  for (int i = 0; i < 6; ++i) {
    int r = rg * 6 + i;
    float sn = hb[(size_t)r * CH + c] + acc[i] + bb;
    slots[(size_t)r * CH + c] = sn;
    if (lastit) {
      int b = r / 3, s5 = r % 3;
      spf[((size_t)(b * CT + t) * CS + s5) * CH + c] = sn;
    }
  }
}

// ================= temporal attention: qkv projection =================
__global__ __launch_bounds__(256) void k_tproj(const float* __restrict__ spf,
                                               const float* __restrict__ ws_c,
                                               const float* __restrict__ b_tq,
                                               const float* __restrict__ b_tk,
                                               const float* __restrict__ b_tv,
                                               float* __restrict__ tqkv) {
  __shared__ float xr[CH];
  int row = blockIdx.x;  // bs*16 + t
  int bs = row >> 4, t = row & 15;
  int b = bs / 3, s = bs % 3;
  const float* x = spf + ((size_t)(b * CT + t) * CS + s) * CH;
  for (int i = threadIdx.x; i < CH; i += 256) xr[i] = x[i];
  __syncthreads();
  for (int p = 0; p < 6; ++p) {
    int j = p * 256 + threadIdx.x;
    const float* wT; const float* bb; int jj;
    if (j < 512)      { wT = ws_c + OFS_WTQT; bb = b_tq; jj = j; }
    else if (j < 1024){ wT = ws_c + OFS_WTKT; bb = b_tk; jj = j - 512; }
    else              { wT = ws_c + OFS_WTVT; bb = b_tv; jj = j - 1024; }
    float acc = bb[jj];
    for (int h = 0; h < CH; ++h) acc += xr[h] * wT[h * CH + jj];
    tqkv[(size_t)row * CH3 + j] = acc;
  }
}

// ================= temporal attention: per (track, head) =================
__global__ __launch_bounds__(64) void k_tattn(const float* __restrict__ tqkv,
                                              float* __restrict__ ob) {
  __shared__ float qs[16][68], ks[16][68], vs[16][68], sc[16][20];
  int bs = blockIdx.x >> 3, hh = blockIdx.x & 7;
  int lane = threadIdx.x;
  for (int i = 0; i < 16; ++i) {
    const float* base = tqkv + (size_t)(bs * 16 + i) * CH3 + hh * 64;
    qs[i][lane] = base[lane];
    ks[i][lane] = base[512 + lane];
    vs[i][lane] = base[1024 + lane];
  }
  __syncthreads();
  for (int u = 0; u < 4; ++u) {
    int ee = u * 64 + lane;
    int i = ee >> 4, j = ee & 15;
    float acc = 0.f;
    for (int d = 0; d < 64; ++d) acc += qs[i][d] * ks[j][d];
    sc[i][j] = acc * 0.125f;  // 1/sqrt(64)
  }
  __syncthreads();
  if (lane < 16) {
    float mx = -1e30f;
    for (int j = 0; j < 16; ++j) mx = fmaxf(mx, sc[lane][j]);
    float sum = 0.f;
    for (int j = 0; j < 16; ++j) { float ev = expf(sc[lane][j] - mx); sc[lane][j] = ev; sum += ev; }
    float inv = 1.f / sum;
    for (int j = 0; j < 16; ++j) sc[lane][j] *= inv;
  }
  __syncthreads();
  for (int i = 0; i < 16; ++i) {
    float acc = 0.f;
    for (int j = 0; j < 16; ++j) acc += sc[i][j] * vs[j][lane];
    ob[(size_t)(bs * 16 + i) * CH + hh * 64 + lane] = acc;
  }
}

// ================= temporal out-proj + residual + LN + mean =================
__global__ __launch_bounds__(256) void k_tout(const float* __restrict__ ob,
                                              const float* __restrict__ spf,
                                              const float* __restrict__ ws_c,
                                              const float* __restrict__ b_to,
                                              const float* __restrict__ g_lt,
                                              const float* __restrict__ b_lt,
                                              float* __restrict__ agg) {
  __shared__ float orow[CH], rrow[CH], red[8];
  int row = blockIdx.x;
  int bs = row >> 4, t = row & 15;
  int b = bs / 3, s = bs % 3;
  const float* x = spf + ((size_t)(b * CT + t) * CS + s) * CH;
  const float* o = ob + (size_t)row * CH;
  for (int i = threadIdx.x; i < CH; i += 256) orow[i] = o[i];
  __syncthreads();
  const float* wto = ws_c + OFS_WTOT;
  for (int p = 0; p < 2; ++p) {
    int j = p * 256 + threadIdx.x;
    float acc = b_to[j];
    for (int c = 0; c < CH; ++c) acc += orow[c] * wto[c * CH + j];
    rrow[j] = acc + x[j];
  }
  __syncthreads();
  float part = rrow[threadIdx.x] + rrow[threadIdx.x + 256];
  for (int o2 = 32; o2; o2 >>= 1) part += __shfl_xor(part, o2);
  if ((threadIdx.x & 63) == 0) red[threadIdx.x >> 6] = part;
  __syncthreads();
  float mean = (red[0] + red[1] + red[2] + red[3]) * (1.f / CH);
  float d0 = rrow[threadIdx.x] - mean, d1 = rrow[threadIdx.x + 256] - mean;
  float p2 = d0 * d0 + d1 * d1;
  for (int o2 = 32; o2; o2 >>= 1) p2 += __shfl_xor(p2, o2);
  __syncthreads();
  if ((threadIdx.x & 63) == 0) red[(threadIdx.x >> 6) + 4] = p2;
  __syncthreads();
  float rstd = rsqrtf((red[4] + red[5] + red[6] + red[7]) * (1.f / CH) + 1e-5f);
  for (int p = 0; p < 2; ++p) {
    int j = p * 256 + threadIdx.x;
    float xt = (rrow[j] - mean) * rstd * g_lt[j] + b_lt[j];
    atomicAdd(&agg[(size_t)bs * CH + j], xt * (1.f / CT));
  }
}

// ================= launch =================
extern "C" void kernel_launch(void* const* d_in, const int* in_sizes, int n_in,
                              void* d_out, int out_size, void* d_ws, size_t ws_size,
                              hipStream_t stream) {
  (void)in_sizes; (void)n_in; (void)out_size; (void)ws_size;
  const float* visual = (const float*)d_in[0];
  const float* noise  = (const float*)d_in[1];
  const float* mu     = (const float*)d_in[2];
  const float* sigma  = (const float*)d_in[3];
  const float* w_in   = (const float*)d_in[4];
  const float* b_in   = (const float*)d_in[5];
  const float* g_lin  = (const float*)d_in[6];
  const float* b_lin  = (const float*)d_in[7];
  const float* w_m1p  = (const float*)d_in[8];
  const float* b_m1p  = (const float*)d_in[9];
  const float* w_m2p  = (const float*)d_in[10];
  const float* b_m2p  = (const float*)d_in[11];
  const float* w_q    = (const float*)d_in[12];
  const float* w_k    = (const float*)d_in[13];
  const float* w_v    = (const float*)d_in[14];
  const float* w_ih   = (const float*)d_in[15];
  const float* w_hh   = (const float*)d_in[16];
  const float* b_ih   = (const float*)d_in[17];
  const float* b_hh   = (const float*)d_in[18];
  const float* g_ls   = (const float*)d_in[19];
  const float* b_ls   = (const float*)d_in[20];
  const float* g_lm   = (const float*)d_in[21];
  const float* b_lm   = (const float*)d_in[22];
  const float* w_mlp1 = (const float*)d_in[23];
  const float* b_mlp1 = (const float*)d_in[24];
  const float* w_mlp2 = (const float*)d_in[25];
  const float* b_mlp2 = (const float*)d_in[26];
  const float* w_tq   = (const float*)d_in[27];
  const float* b_tq   = (const float*)d_in[28];
  const float* w_tk   = (const float*)d_in[29];
  const float* b_tk   = (const float*)d_in[30];
  const float* w_tv   = (const float*)d_in[31];
  const float* b_tv   = (const float*)d_in[32];
  const float* w_to   = (const float*)d_in[33];
  const float* b_to   = (const float*)d_in[34];
  const float* g_lt   = (const float*)d_in[35];
  const float* b_lt   = (const float*)d_in[36];

  float* ws  = (float*)d_ws;
  float* out = (float*)d_out;
  float* spf = out + 12288;
  float* att = out + 12288 + 196608;

  hipLaunchKernelGGL(k_init, dim3(48), dim3(256), 0, stream, noise, mu, sigma, ws, out);
  hipLaunchKernelGGL(k_transpose, dim3(32, 48, 9), dim3(256), 0, stream,
                     w_q, w_hh, w_ih, w_mlp1, w_mlp2, w_to, w_tq, w_tk, w_tv, ws);
  // Stage 1
  hipLaunchKernelGGL(k_p1, dim3(4, 256), dim3(256), 0, stream,
                     visual, w_in, b_in, ws + OFS_P1);
  hipLaunchKernelGGL(k_rowstats, dim3(CM / 4), dim3(256), 0, stream,
                     ws + OFS_P1, ws + OFS_ST);
  hipLaunchKernelGGL(k_m1, dim3(4, 256), dim3(256), 0, stream,
                     visual, w_m1p, b_m1p, ws + OFS_M1);
  hipLaunchKernelGGL(k_feats, dim3(4, 256), dim3(256), 0, stream,
                     ws + OFS_M1, w_m2p, b_m2p, ws + OFS_ST, g_lin, b_lin, ws + OFS_P1);
  hipLaunchKernelGGL(k_kv, dim3(8, 256), dim3(256), 0, stream,
                     ws + OFS_P1, w_k, w_v, ws + OFS_M1, ws + OFS_V);
  // Stage 2: phase-split scan v2 — column-slice x all-rows blocks, 5 kernels/iter
  for (int t = 0; t < CT; ++t) {
    for (int it = 0; it < NITER; ++it) {
      int lastit = (it == NITER - 1) ? 1 : 0;
      hipLaunchKernelGGL(ph_A, dim3(32),    dim3(256), 0, stream, ws, g_ls, b_ls, b_hh);
      hipLaunchKernelGGL(ph_B, dim3(2, 8),  dim3(256), 0, stream, ws, att, t, lastit);
      hipLaunchKernelGGL(ph_C, dim3(16),    dim3(256), 0, stream, ws, b_ih);
      hipLaunchKernelGGL(ph_D, dim3(16),    dim3(256), 0, stream, ws, g_lm, b_lm, b_mlp1);
      hipLaunchKernelGGL(ph_E, dim3(8),     dim3(256), 0, stream, ws, b_mlp2, spf, t, lastit);
    }
  }
  // Stage 3: temporal attention
  hipLaunchKernelGGL(k_tproj, dim3(384), dim3(256), 0, stream,
                     spf, ws, b_tq, b_tk, b_tv, ws + OFS_TQKV);
  hipLaunchKernelGGL(k_tattn, dim3(192), dim3(64), 0, stream,
                     ws + OFS_TQKV, ws + OFS_TO);
  hipLaunchKernelGGL(k_tout, dim3(384), dim3(256), 0, stream,
                     ws + OFS_TO, spf, ws, b_to, g_lt, b_lt, out);
}

// Round 8
// 6377.977 us; speedup vs baseline: 2.0051x; 2.0051x over previous
//
#include <hip/hip_runtime.h>
#include <math.h>

// ---------------- problem constants ----------------
#define CB 8
#define CT 16
#define CN 256
#define CD 1280
#define CH 512
#define CS 3
#define CM (CB*CT*CN)      // 32768 rows
#define CBS (CB*CS)        // 24
#define CH3 (3*CH)         // 1536
#define CH2 (2*CH)         // 1024
#define NITER 3

// ---------------- workspace layout (float offsets) ----------------
#define OFS_P1   0ULL                       // P1, later feats (in-place): CM*CH
#define OFS_M1   16777216ULL                // M1, later k_buf (overwrite): CM*CH
#define OFS_V    33554432ULL                // v buf (row-major): CM*CH
#define OFS_ST   50331648ULL                // rowstats: CM*2
#define OFS_WTOT 50397184ULL                // stage-3 transposes
#define OFS_WTQT (OFS_WTOT + 262144ULL)
#define OFS_WTKT (OFS_WTQT + 262144ULL)
#define OFS_WTVT (OFS_WTKT + 262144ULL)
#define OFS_SLOTS (OFS_WTVT + 262144ULL)    // 24*512
#define OFS_Q    (OFS_SLOTS + 12288ULL)     // 24*512
#define OFS_GH   (OFS_Q + 12288ULL)         // 24*1536
#define OFS_ATTN (OFS_GH + 36864ULL)        // 24*256
#define OFS_U    (OFS_ATTN + 6144ULL)       // 24*512
#define OFS_Z    (OFS_U + 12288ULL)         // (unused)
#define OFS_H    (OFS_Z + 32ULL)            // 24*512
#define OFS_Y    (OFS_H + 12288ULL)         // 24*1024
#define OFS_TQKV (OFS_Y + 24576ULL)         // 384*1536
#define OFS_TO   (OFS_TQKV + 589824ULL)     // 384*512

// ---------------- GEMM tiling ----------------
#define BM 128
#define BN 128
#define BK 8

// ================= init: slots0, zero agg =================
__global__ __launch_bounds__(256) void k_init(const float* __restrict__ noise,
                                              const float* __restrict__ mu,
                                              const float* __restrict__ sigma,
                                              float* __restrict__ ws,
                                              float* __restrict__ out) {
  int i = blockIdx.x * 256 + threadIdx.x;
  if (i < 12288) {
    int sj = i % 1536;  // (s,h) index into mu/sigma [1,3,512]
    ws[OFS_SLOTS + i] = mu[sj] + sigma[sj] * noise[i];
    out[i] = 0.0f;      // zero slots_agg accumulation region
  }
}

// ================= weight transposes (k-major) for stage-3 kernels =================
__global__ __launch_bounds__(256) void k_transpose(const float* __restrict__ w_to,
                                                   const float* __restrict__ w_tq,
                                                   const float* __restrict__ w_tk,
                                                   const float* __restrict__ w_tv,
                                                   float* __restrict__ ws) {
  const float* src; float* dst;
  switch (blockIdx.z) {
    case 0: src = w_to; dst = ws + OFS_WTOT; break;
    case 1: src = w_tq; dst = ws + OFS_WTQT; break;
    case 2: src = w_tk; dst = ws + OFS_WTKT; break;
    default: src = w_tv; dst = ws + OFS_WTVT; break;
  }
  const int R = 512, C = 512;
  int r0 = blockIdx.y * 32, c0 = blockIdx.x * 32;
  __shared__ float tile[32][33];
  int tx = threadIdx.x & 31, ty = threadIdx.x >> 5;  // 32 x 8
  for (int i = ty; i < 32; i += 8)
    tile[i][tx] = src[(size_t)(r0 + i) * C + c0 + tx];
  __syncthreads();
  for (int i = ty; i < 32; i += 8)
    dst[(size_t)(c0 + i) * R + r0 + tx] = tile[tx][i];
}

// ================= GEMM 1: P1 = visual @ w_in.T + b_in =================
__global__ __launch_bounds__(256) void k_p1(const float* __restrict__ A,
                                            const float* __restrict__ W,
                                            const float* __restrict__ bias,
                                            float* __restrict__ Cout) {
  __shared__ float As[BK][BM + 4];
  __shared__ float Bs[BK][BN + 4];
  const int tid = threadIdx.x;
  const int m0 = blockIdx.y * BM;
  const int n0 = blockIdx.x * BN;
  const int tx = tid & 15, ty = tid >> 4;
  float acc[8][8];
#pragma unroll
  for (int i = 0; i < 8; ++i)
#pragma unroll
    for (int j = 0; j < 8; ++j) acc[i][j] = 0.f;

  for (int kb = 0; kb < CD; kb += BK) {
#pragma unroll
    for (int p = 0; p < 4; ++p) {
      int r = (tid >> 3) + p * 32;
      int k = tid & 7;
      As[k][r] = A[(size_t)(m0 + r) * CD + kb + k];
      Bs[k][r] = W[(size_t)(n0 + r) * CD + kb + k];
    }
    __syncthreads();
#pragma unroll
    for (int kk = 0; kk < BK; ++kk) {
      float av[8], bv[8];
      *(float4*)&av[0] = *(const float4*)&As[kk][ty * 8];
      *(float4*)&av[4] = *(const float4*)&As[kk][ty * 8 + 4];
      *(float4*)&bv[0] = *(const float4*)&Bs[kk][tx * 8];
      *(float4*)&bv[4] = *(const float4*)&Bs[kk][tx * 8 + 4];
#pragma unroll
      for (int i = 0; i < 8; ++i)
#pragma unroll
        for (int j = 0; j < 8; ++j) acc[i][j] += av[i] * bv[j];
    }
    __syncthreads();
  }
#pragma unroll
  for (int i = 0; i < 8; ++i) {
    int m = m0 + ty * 8 + i;
#pragma unroll
    for (int j = 0; j < 8; ++j) {
      int n = n0 + tx * 8 + j;
      Cout[(size_t)m * CH + n] = acc[i][j] + bias[n];
    }
  }
}

// ================= GEMM 2: M1 = relu(motion @ w_m1p.T + b_m1p) =================
__global__ __launch_bounds__(256) void k_m1(const float* __restrict__ A,
                                            const float* __restrict__ W,
                                            const float* __restrict__ bias,
                                            float* __restrict__ Cout) {
  __shared__ float As[BK][BM + 4];
  __shared__ float Bs[BK][BN + 4];
  const int tid = threadIdx.x;
  const int m0 = blockIdx.y * BM;
  const int n0 = blockIdx.x * BN;
  const int tx = tid & 15, ty = tid >> 4;
  const int frame = (m0 >> 8);         // (b*16 + t)
  const int tfrm = frame & 15;
  float acc[8][8];
#pragma unroll
  for (int i = 0; i < 8; ++i)
#pragma unroll
    for (int j = 0; j < 8; ++j) acc[i][j] = 0.f;

  for (int kb = 0; kb < CD; kb += BK) {
#pragma unroll
    for (int p = 0; p < 4; ++p) {
      int r = (tid >> 3) + p * 32;
      int k = tid & 7;
      float mv = 0.f;
      if (tfrm < 15) {
        float cur = A[(size_t)(m0 + r) * CD + kb + k];
        float nxt = A[(size_t)(m0 + r + 256) * CD + kb + k];
        mv = nxt - cur;
      }
      As[k][r] = mv;
      Bs[k][r] = W[(size_t)(n0 + r) * CD + kb + k];
    }
    __syncthreads();
#pragma unroll
    for (int kk = 0; kk < BK; ++kk) {
      float av[8], bv[8];
      *(float4*)&av[0] = *(const float4*)&As[kk][ty * 8];
      *(float4*)&av[4] = *(const float4*)&As[kk][ty * 8 + 4];
      *(float4*)&bv[0] = *(const float4*)&Bs[kk][tx * 8];
      *(float4*)&bv[4] = *(const float4*)&Bs[kk][tx * 8 + 4];
#pragma unroll
      for (int i = 0; i < 8; ++i)
#pragma unroll
        for (int j = 0; j < 8; ++j) acc[i][j] += av[i] * bv[j];
    }
    __syncthreads();
  }
#pragma unroll
  for (int i = 0; i < 8; ++i) {
    int m = m0 + ty * 8 + i;
#pragma unroll
    for (int j = 0; j < 8; ++j) {
      int n = n0 + tx * 8 + j;
      Cout[(size_t)m * CH + n] = fmaxf(acc[i][j] + bias[n], 0.f);
    }
  }
}

// ================= row stats of P1 for LN =================
__global__ __launch_bounds__(256) void k_rowstats(const float* __restrict__ P1,
                                                  float* __restrict__ st) {
  int row = blockIdx.x * 4 + (threadIdx.x >> 6);
  int lane = threadIdx.x & 63;
  const float* r = P1 + (size_t)row * CH;
  float4 x0 = *(const float4*)&r[lane * 8];
  float4 x1 = *(const float4*)&r[lane * 8 + 4];
  float s = x0.x + x0.y + x0.z + x0.w + x1.x + x1.y + x1.z + x1.w;
  for (int o = 32; o; o >>= 1) s += __shfl_xor(s, o);
  float mean = s * (1.f / CH);
  float d, s2 = 0.f;
  d = x0.x - mean; s2 += d * d; d = x0.y - mean; s2 += d * d;
  d = x0.z - mean; s2 += d * d; d = x0.w - mean; s2 += d * d;
  d = x1.x - mean; s2 += d * d; d = x1.y - mean; s2 += d * d;
  d = x1.z - mean; s2 += d * d; d = x1.w - mean; s2 += d * d;
  for (int o = 32; o; o >>= 1) s2 += __shfl_xor(s2, o);
  if (lane == 0) {
    st[2 * row] = mean;
    st[2 * row + 1] = rsqrtf(s2 * (1.f / CH) + 1e-5f);
  }
}

// ================= GEMM 3: feats = LN(P1)*g+b + 0.5*(M1 @ w_m2p.T + b_m2p), in-place =================
__global__ __launch_bounds__(256) void k_feats(const float* __restrict__ A,  // M1
                                               const float* __restrict__ W,  // w_m2p
                                               const float* __restrict__ bias,
                                               const float* __restrict__ st,
                                               const float* __restrict__ g_ln,
                                               const float* __restrict__ b_ln,
                                               float* __restrict__ P1inout) {
  __shared__ float As[BK][BM + 4];
  __shared__ float Bs[BK][BN + 4];
  const int tid = threadIdx.x;
  const int m0 = blockIdx.y * BM;
  const int n0 = blockIdx.x * BN;
  const int tx = tid & 15, ty = tid >> 4;
  float acc[8][8];
#pragma unroll
  for (int i = 0; i < 8; ++i)
#pragma unroll
    for (int j = 0; j < 8; ++j) acc[i][j] = 0.f;

  for (int kb = 0; kb < CH; kb += BK) {
#pragma unroll
    for (int p = 0; p < 4; ++p) {
      int r = (tid >> 3) + p * 32;
      int k = tid & 7;
      As[k][r] = A[(size_t)(m0 + r) * CH + kb + k];
      Bs[k][r] = W[(size_t)(n0 + r) * CH + kb + k];
    }
    __syncthreads();
#pragma unroll
    for (int kk = 0; kk < BK; ++kk) {
      float av[8], bv[8];
      *(float4*)&av[0] = *(const float4*)&As[kk][ty * 8];
      *(float4*)&av[4] = *(const float4*)&As[kk][ty * 8 + 4];
      *(float4*)&bv[0] = *(const float4*)&Bs[kk][tx * 8];
      *(float4*)&bv[4] = *(const float4*)&Bs[kk][tx * 8 + 4];
#pragma unroll
      for (int i = 0; i < 8; ++i)
#pragma unroll
        for (int j = 0; j < 8; ++j) acc[i][j] += av[i] * bv[j];
    }
    __syncthreads();
  }
#pragma unroll
  for (int i = 0; i < 8; ++i) {
    int m = m0 + ty * 8 + i;
    float mean = st[2 * m], rstd = st[2 * m + 1];
#pragma unroll
    for (int j = 0; j < 8; ++j) {
      int n = n0 + tx * 8 + j;
      size_t idx = (size_t)m * CH + n;
      float p1v = P1inout[idx];
      float v = (p1v - mean) * rstd * g_ln[n] + b_ln[n] + 0.5f * (acc[i][j] + bias[n]);
      P1inout[idx] = v;
    }
  }
}

// ================= GEMM 4: k | v (both row-major) = feats @ [w_k; w_v].T =================
__global__ __launch_bounds__(256) void k_kv(const float* __restrict__ A,  // feats
                                            const float* __restrict__ Wk,
                                            const float* __restrict__ Wv,
                                            float* __restrict__ kbuf,
                                            float* __restrict__ vbuf) {
  __shared__ float As[BK][BM + 4];
  __shared__ float Bs[BK][BN + 4];
  const int tid = threadIdx.x;
  const int m0 = blockIdx.y * BM;
  const int n0 = blockIdx.x * BN;  // 0..1023
  const int tx = tid & 15, ty = tid >> 4;
  const bool khalf = (n0 < 512);
  const float* W = khalf ? (Wk + (size_t)n0 * CH) : (Wv + (size_t)(n0 - 512) * CH);
  float* Out = khalf ? kbuf : vbuf;
  const int nbase = khalf ? n0 : (n0 - 512);
  float acc[8][8];
#pragma unroll
  for (int i = 0; i < 8; ++i)
#pragma unroll
    for (int j = 0; j < 8; ++j) acc[i][j] = 0.f;

  for (int kb = 0; kb < CH; kb += BK) {
#pragma unroll
    for (int p = 0; p < 4; ++p) {
      int r = (tid >> 3) + p * 32;
      int k = tid & 7;
      As[k][r] = A[(size_t)(m0 + r) * CH + kb + k];
      Bs[k][r] = W[(size_t)r * CH + kb + k];
    }
    __syncthreads();
#pragma unroll
    for (int kk = 0; kk < BK; ++kk) {
      float av[8], bv[8];
      *(float4*)&av[0] = *(const float4*)&As[kk][ty * 8];
      *(float4*)&av[4] = *(const float4*)&As[kk][ty * 8 + 4];
      *(float4*)&bv[0] = *(const float4*)&Bs[kk][tx * 8];
      *(float4*)&bv[4] = *(const float4*)&Bs[kk][tx * 8 + 4];
#pragma unroll
      for (int i = 0; i < 8; ++i)
#pragma unroll
        for (int j = 0; j < 8; ++j) acc[i][j] += av[i] * bv[j];
    }
    __syncthreads();
  }
#pragma unroll
  for (int i = 0; i < 8; ++i) {
    int m = m0 + ty * 8 + i;
#pragma unroll
    for (int j = 0; j < 8; ++j) {
      int n = nbase + tx * 8 + j;
      Out[(size_t)m * CH + n] = acc[i][j];
    }
  }
}

// ============================================================================
// Slot-attention scan, phase-split v3: GEMV phases use (16 cols x 16 k-slices)
// per block, each thread accumulating ALL 24 rows over a 32-wide k-slice of
// the ORIGINAL row-major weight (1 cache line), + LDS k-tree reduce.
// Weights read ONCE per phase (v1 re-read 24x) AND grids of 32-128 blocks
// with ~200-400 float4-FMA chains (v2 had 8-32 blocks, 512+ chains).
// ============================================================================

// ---- Phase A: q = LN(slots)@w_q.T (bx<32) ; gh = slots@w_hh.T + b_hh (bx 32..127) ----
__global__ __launch_bounds__(256) void ph_A(float* __restrict__ ws,
                                            const float* __restrict__ w_q_g,
                                            const float* __restrict__ w_hh_g,
                                            const float* __restrict__ g_ls,
                                            const float* __restrict__ b_ls,
                                            const float* __restrict__ b_hh) {
  __shared__ float act[CBS * CH];        // 48 KB
  __shared__ float part[384][17];        // 25.5 KB, padded for reduce
  __shared__ float lm[CBS], lr[CBS];
  const int bx = blockIdx.x;             // 0..127
  const int tid = threadIdx.x;
  const bool isq = (bx < 32);
  const float* slots = ws + OFS_SLOTS;
  for (int i = tid; i < CBS * CH / 4; i += 256)
    ((float4*)act)[i] = ((const float4*)slots)[i];
  __syncthreads();
  if (isq) {
    int wv = tid >> 6, lane = tid & 63;
    for (int rr = 0; rr < 6; ++rr) {
      int r = wv * 6 + rr;
      const float* row = act + r * CH;
      float s = 0.f;
#pragma unroll
      for (int i = 0; i < 8; ++i) s += row[lane + 64 * i];
      for (int o = 32; o; o >>= 1) s += __shfl_xor(s, o);
      float mean = s * (1.f / CH);
      float s2 = 0.f;
#pragma unroll
      for (int i = 0; i < 8; ++i) { float d = row[lane + 64 * i] - mean; s2 += d * d; }
      for (int o = 32; o; o >>= 1) s2 += __shfl_xor(s2, o);
      if (lane == 0) { lm[r] = mean; lr[r] = rsqrtf(s2 * (1.f / CH) + 1e-5f); }
    }
    __syncthreads();
    for (int i = tid; i < CBS * CH; i += 256) {
      int r = i >> 9, k = i & 511;
      act[i] = (act[i] - lm[r]) * lr[r] * g_ls[k] + b_ls[k];
    }
    __syncthreads();
  }
  const int cl = tid & 15, ks = tid >> 4;          // 16 cols x 16 k-slices(32)
  const int c = (isq ? bx : (bx - 32)) * 16 + cl;
  const float* wrow = (isq ? w_q_g : w_hh_g) + (size_t)c * CH + ks * 32;
  float acc[CBS];
#pragma unroll
  for (int r = 0; r < CBS; ++r) acc[r] = 0.f;
#pragma unroll
  for (int j = 0; j < 8; ++j) {
    float4 w4 = *(const float4*)&wrow[j * 4];
    const float* ab = act + ks * 32 + j * 4;
#pragma unroll
    for (int r = 0; r < CBS; ++r) {
      float4 a4 = *(const float4*)&ab[r * CH];
      acc[r] += a4.x * w4.x + a4.y * w4.y + a4.z * w4.z + a4.w * w4.w;
    }
  }
#pragma unroll
  for (int r = 0; r < CBS; ++r) part[cl * CBS + r][ks] = acc[r];
  __syncthreads();
  for (int o = tid; o < 384; o += 256) {
    float s = 0.f;
#pragma unroll
    for (int q2 = 0; q2 < 16; ++q2) s += part[o][q2];
    int cl2 = o / CBS, r = o - cl2 * CBS;
    if (isq) {
      ws[OFS_Q + (size_t)r * CH + bx * 16 + cl2] = s;
    } else {
      int cg = (bx - 32) * 16 + cl2;
      ws[OFS_GH + (size_t)r * CH3 + cg] = s + b_hh[cg];
    }
  }
}

// ---- Phase B1: logits -> softmax over slots -> attn. grid (8, 8) ----
__global__ __launch_bounds__(256) void ph_B1(float* __restrict__ ws,
                                             float* __restrict__ att,
                                             int t, int lastit) {
  const int b = blockIdx.y;        // 0..7
  const int chunk = blockIdx.x;    // 0..7 (32 n each)
  const int wv = threadIdx.x >> 6, lane = threadIdx.x & 63;
  const float* qb = ws + OFS_Q + (size_t)b * 3 * CH;
  const float* kbuf = ws + OFS_M1;
  float* attnb = ws + OFS_ATTN;
  const float scale = 0.04419417382415922f;  // 512^-0.5
#pragma unroll
  for (int i = 0; i < 8; ++i) {
    int n = chunk * 32 + wv * 8 + i;
    const float* krow = kbuf + ((size_t)((b * CT + t) * CN + n)) * CH;
    float p0 = 0.f, p1 = 0.f, p2 = 0.f;
#pragma unroll
    for (int u = 0; u < 2; ++u) {
      int k = lane * 8 + u * 4;
      float4 kk = *(const float4*)&krow[k];
      float4 a0 = *(const float4*)&qb[k];
      float4 a1 = *(const float4*)&qb[CH + k];
      float4 a2 = *(const float4*)&qb[2 * CH + k];
      p0 += a0.x * kk.x + a0.y * kk.y + a0.z * kk.z + a0.w * kk.w;
      p1 += a1.x * kk.x + a1.y * kk.y + a1.z * kk.z + a1.w * kk.w;
      p2 += a2.x * kk.x + a2.y * kk.y + a2.z * kk.z + a2.w * kk.w;
    }
    for (int o = 32; o; o >>= 1) {
      p0 += __shfl_xor(p0, o); p1 += __shfl_xor(p1, o); p2 += __shfl_xor(p2, o);
    }
    p0 *= scale; p1 *= scale; p2 *= scale;
    float mx = fmaxf(p0, fmaxf(p1, p2));
    float e0 = expf(p0 - mx), e1 = expf(p1 - mx), e2 = expf(p2 - mx);
    float inv = 1.f / (e0 + e1 + e2);
    if (lane < 3) {
      float a = (lane == 0 ? e0 : (lane == 1 ? e1 : e2)) * inv;
      attnb[(b * 3 + lane) * CN + n] = a;
      if (lastit)
        att[((size_t)(b * CT + t) * CS + lane) * CN + n] = a;
    }
  }
}

// ---- Phase B2: U = (attn @ v) / Z. grid (2, 24) ----
__global__ __launch_bounds__(256) void ph_B2(float* __restrict__ ws, int t) {
  const int r = blockIdx.y;        // 0..23
  const int chunk = blockIdx.x;    // 0..1
  const int b = r / 3;
  const int tid = threadIdx.x;
  __shared__ float arow[CN], red[4];
  __shared__ float iz;
  const float* attnb = ws + OFS_ATTN + (size_t)r * CN;
  float a = attnb[tid];
  arow[tid] = a;
  float z = a;
  for (int o = 32; o; o >>= 1) z += __shfl_xor(z, o);
  if ((tid & 63) == 0) red[tid >> 6] = z;
  __syncthreads();
  if (tid == 0) iz = 1.f / (red[0] + red[1] + red[2] + red[3] + 1e-8f);
  __syncthreads();
  int c = chunk * 256 + tid;
  const float* v = ws + OFS_V + ((size_t)(b * CT + t) * CN) * CH + c;
  float a0 = 0.f, a1 = 0.f, a2 = 0.f, a3 = 0.f;
  for (int n = 0; n < CN; n += 4) {
    a0 += arow[n]     * v[(size_t)(n)     * CH];
    a1 += arow[n + 1] * v[(size_t)(n + 1) * CH];
    a2 += arow[n + 2] * v[(size_t)(n + 2) * CH];
    a3 += arow[n + 3] * v[(size_t)(n + 3) * CH];
  }
  ws[OFS_U + (size_t)r * CH + c] = (a0 + a1 + a2 + a3) * iz;
}

// ---- Phase C: gi = U@w_ih.T + b_ih (24 cols/block) ; GRU -> h. grid 64 ----
__global__ __launch_bounds__(256) void ph_C(float* __restrict__ ws,
                                            const float* __restrict__ w_ih_g,
                                            const float* __restrict__ b_ih) {
  __shared__ float act[CBS * CH];        // 48 KB (U)
  __shared__ float part[576][9];         // 20.3 KB
  __shared__ float gil[576];             // 2.3 KB
  const int bx = blockIdx.x;             // 0..63 -> j0 = bx*8
  const int tid = threadIdx.x;
  const float* U = ws + OFS_U;
  for (int i = tid; i < CBS * CH / 4; i += 256)
    ((float4*)act)[i] = ((const float4*)U)[i];
  __syncthreads();
  if (tid < 192) {
    const int cidx = tid % 24, ks = tid / 24;   // 24 cols x 8 k-slices(64)
    const int gate = cidx >> 3, jl = cidx & 7;
    const int col = gate * 512 + bx * 8 + jl;
    const float* wrow = w_ih_g + (size_t)col * CH + ks * 64;
    float acc[CBS];
#pragma unroll
    for (int r = 0; r < CBS; ++r) acc[r] = 0.f;
#pragma unroll
    for (int j = 0; j < 16; ++j) {
      float4 w4 = *(const float4*)&wrow[j * 4];
      const float* ab = act + ks * 64 + j * 4;
#pragma unroll
      for (int r = 0; r < CBS; ++r) {
        float4 a4 = *(const float4*)&ab[r * CH];
        acc[r] += a4.x * w4.x + a4.y * w4.y + a4.z * w4.z + a4.w * w4.w;
      }
    }
#pragma unroll
    for (int r = 0; r < CBS; ++r) part[cidx * CBS + r][ks] = acc[r];
  }
  __syncthreads();
  for (int o = tid; o < 576; o += 256) {
    float s = 0.f;
#pragma unroll
    for (int q2 = 0; q2 < 8; ++q2) s += part[o][q2];
    int cidx = o / CBS;
    int gate = cidx >> 3, jl = cidx & 7;
    gil[o] = s + b_ih[gate * 512 + bx * 8 + jl];
  }
  __syncthreads();
  if (tid < 192) {
    const int r = tid >> 3, jl = tid & 7;
    const int j = bx * 8 + jl;
    float ir  = gil[(jl)      * CBS + r];
    float iz2 = gil[(8 + jl)  * CBS + r];
    float inn = gil[(16 + jl) * CBS + r];
    const float* gh = ws + OFS_GH;
    float hr = gh[(size_t)r * CH3 + j];
    float hz = gh[(size_t)r * CH3 + CH + j];
    float hn = gh[(size_t)r * CH3 + 2 * CH + j];
    float rr = 1.f / (1.f + expf(-(ir + hr)));
    float zz = 1.f / (1.f + expf(-(iz2 + hz)));
    float nn = tanhf(inn + rr * hn);
    float sl = ws[OFS_SLOTS + (size_t)r * CH + j];
    ws[OFS_H + (size_t)r * CH + j] = (1.f - zz) * nn + zz * sl;
  }
}

// ---- Phase D: y = gelu(LN(h)@w_mlp1.T + b_m1). grid 64 ----
__global__ __launch_bounds__(256) void ph_D(float* __restrict__ ws,
                                            const float* __restrict__ w_m1_g,
                                            const float* __restrict__ g_lm,
                                            const float* __restrict__ b_lm,
                                            const float* __restrict__ b_m1) {
  __shared__ float act[CBS * CH];        // 48 KB
  __shared__ float part[384][17];        // 25.5 KB
  __shared__ float lm[CBS], lr[CBS];
  const int bx = blockIdx.x;             // 0..63 -> cols bx*16..+16 of 1024
  const int tid = threadIdx.x;
  const float* hb = ws + OFS_H;
  for (int i = tid; i < CBS * CH / 4; i += 256)
    ((float4*)act)[i] = ((const float4*)hb)[i];
  __syncthreads();
  {
    int wv = tid >> 6, lane = tid & 63;
    for (int rr = 0; rr < 6; ++rr) {
      int r = wv * 6 + rr;
      const float* row = act + r * CH;
      float s = 0.f;
#pragma unroll
      for (int i = 0; i < 8; ++i) s += row[lane + 64 * i];
      for (int o = 32; o; o >>= 1) s += __shfl_xor(s, o);
      float mean = s * (1.f / CH);
      float s2 = 0.f;
#pragma unroll
      for (int i = 0; i < 8; ++i) { float d = row[lane + 64 * i] - mean; s2 += d * d; }
      for (int o = 32; o; o >>= 1) s2 += __shfl_xor(s2, o);
      if (lane == 0) { lm[r] = mean; lr[r] = rsqrtf(s2 * (1.f / CH) + 1e-5f); }
    }
  }
  __syncthreads();
  for (int i = tid; i < CBS * CH; i += 256) {
    int r = i >> 9, k = i & 511;
    act[i] = (act[i] - lm[r]) * lr[r] * g_lm[k] + b_lm[k];
  }
  __syncthreads();
  const int cl = tid & 15, ks = tid >> 4;
  const int c = bx * 16 + cl;
  const float* wrow = w_m1_g + (size_t)c * CH + ks * 32;
  float acc[CBS];
#pragma unroll
  for (int r = 0; r < CBS; ++r) acc[r] = 0.f;
#pragma unroll
  for (int j = 0; j < 8; ++j) {
    float4 w4 = *(const float4*)&wrow[j * 4];
    const float* ab = act + ks * 32 + j * 4;
#pragma unroll
    for (int r = 0; r < CBS; ++r) {
      float4 a4 = *(const float4*)&ab[r * CH];
      acc[r] += a4.x * w4.x + a4.y * w4.y + a4.z * w4.z + a4.w * w4.w;
    }
  }
#pragma unroll
  for (int r = 0; r < CBS; ++r) part[cl * CBS + r][ks] = acc[r];
  __syncthreads();
  for (int o = tid; o < 384; o += 256) {
    float s = 0.f;
#pragma unroll
    for (int q2 = 0; q2 < 16; ++q2) s += part[o][q2];
    int cl2 = o / CBS, r = o - cl2 * CBS;
    int c2 = bx * 16 + cl2;
    float x = s + b_m1[c2];
    ws[OFS_Y + (size_t)r * CH2 + c2] = 0.5f * x * (1.f + erff(x * 0.70710678118654752f));
  }
}

// ---- Phase E: slots' = h + y@w_mlp2.T + b_m2. grid 32 ----
__global__ __launch_bounds__(256) void ph_E(float* __restrict__ ws,
                                            const float* __restrict__ w_m2_g,
                                            const float* __restrict__ b_m2,
                                            float* __restrict__ spf,
                                            int t, int lastit) {
  __shared__ float act[CBS * CH2];       // 96 KB (y)
  __shared__ float part[384][17];        // 25.5 KB -> 121.5 KB total
  const int bx = blockIdx.x;             // 0..31 -> cols bx*16..+16 of 512
  const int tid = threadIdx.x;
  const float* yb = ws + OFS_Y;
  for (int i = tid; i < CBS * CH2 / 4; i += 256)
    ((float4*)act)[i] = ((const float4*)yb)[i];
  __syncthreads();
  const int cl = tid & 15, ks = tid >> 4;   // 16 cols x 16 k-slices(64)
  const int c = bx * 16 + cl;
  const float* wrow = w_m2_g + (size_t)c * CH2 + ks * 64;
  float acc[CBS];
#pragma unroll
  for (int r = 0; r < CBS; ++r) acc[r] = 0.f;
#pragma unroll
  for (int j = 0; j < 16; ++j) {
    float4 w4 = *(const float4*)&wrow[j * 4];
    const float* ab = act + ks * 64 + j * 4;
#pragma unroll
    for (int r = 0; r < CBS; ++r) {
      float4 a4 = *(const float4*)&ab[r * CH2];
      acc[r] += a4.x * w4.x + a4.y * w4.y + a4.z * w4.z + a4.w * w4.w;
    }
  }
#pragma unroll
  for (int r = 0; r < CBS; ++r) part[cl * CBS + r][ks] = acc[r];
  __syncthreads();
  for (int o = tid; o < 384; o += 256) {
    float s = 0.f;
#pragma unroll
    for (int q2 = 0; q2 < 16; ++q2) s += part[o][q2];
    int cl2 = o / CBS, r = o - cl2 * CBS;
    int c2 = bx * 16 + cl2;
    float sn = ws[OFS_H + (size_t)r * CH + c2] + s + b_m2[c2];
    ws[OFS_SLOTS + (size_t)r * CH + c2] = sn;
    if (lastit) {
      int b = r / 3, s5 = r % 3;
      spf[((size_t)(b * CT + t) * CS + s5) * CH + c2] = sn;
    }
  }
}

// ================= temporal attention: qkv projection =================
__global__ __launch_bounds__(256) void k_tproj(const float* __restrict__ spf,
                                               const float* __restrict__ ws_c,
                                               const float* __restrict__ b_tq,
                                               const float* __restrict__ b_tk,
                                               const float* __restrict__ b_tv,
                                               float* __restrict__ tqkv) {
  __shared__ float xr[CH];
  int row = blockIdx.x;  // bs*16 + t
  int bs = row >> 4, t = row & 15;
  int b = bs / 3, s = bs % 3;
  const float* x = spf + ((size_t)(b * CT + t) * CS + s) * CH;
  for (int i = threadIdx.x; i < CH; i += 256) xr[i] = x[i];
  __syncthreads();
  for (int p = 0; p < 6; ++p) {
    int j = p * 256 + threadIdx.x;
    const float* wT; const float* bb; int jj;
    if (j < 512)      { wT = ws_c + OFS_WTQT; bb = b_tq; jj = j; }
    else if (j < 1024){ wT = ws_c + OFS_WTKT; bb = b_tk; jj = j - 512; }
    else              { wT = ws_c + OFS_WTVT; bb = b_tv; jj = j - 1024; }
    float acc = bb[jj];
    for (int h = 0; h < CH; ++h) acc += xr[h] * wT[h * CH + jj];
    tqkv[(size_t)row * CH3 + j] = acc;
  }
}

// ================= temporal attention: per (track, head) =================
__global__ __launch_bounds__(64) void k_tattn(const float* __restrict__ tqkv,
                                              float* __restrict__ ob) {
  __shared__ float qs[16][68], ks[16][68], vs[16][68], sc[16][20];
  int bs = blockIdx.x >> 3, hh = blockIdx.x & 7;
  int lane = threadIdx.x;
  for (int i = 0; i < 16; ++i) {
    const float* base = tqkv + (size_t)(bs * 16 + i) * CH3 + hh * 64;
    qs[i][lane] = base[lane];
    ks[i][lane] = base[512 + lane];
    vs[i][lane] = base[1024 + lane];
  }
  __syncthreads();
  for (int u = 0; u < 4; ++u) {
    int ee = u * 64 + lane;
    int i = ee >> 4, j = ee & 15;
    float acc = 0.f;
    for (int d = 0; d < 64; ++d) acc += qs[i][d] * ks[j][d];
    sc[i][j] = acc * 0.125f;  // 1/sqrt(64)
  }
  __syncthreads();
  if (lane < 16) {
    float mx = -1e30f;
    for (int j = 0; j < 16; ++j) mx = fmaxf(mx, sc[lane][j]);
    float sum = 0.f;
    for (int j = 0; j < 16; ++j) { float ev = expf(sc[lane][j] - mx); sc[lane][j] = ev; sum += ev; }
    float inv = 1.f / sum;
    for (int j = 0; j < 16; ++j) sc[lane][j] *= inv;
  }
  __syncthreads();
  for (int i = 0; i < 16; ++i) {
    float acc = 0.f;
    for (int j = 0; j < 16; ++j) acc += sc[i][j] * vs[j][lane];
    ob[(size_t)(bs * 16 + i) * CH + hh * 64 + lane] = acc;
  }
}

// ================= temporal out-proj + residual + LN + mean =================
__global__ __launch_bounds__(256) void k_tout(const float* __restrict__ ob,
                                              const float* __restrict__ spf,
                                              const float* __restrict__ ws_c,
                                              const float* __restrict__ b_to,
                                              const float* __restrict__ g_lt,
                                              const float* __restrict__ b_lt,
                                              float* __restrict__ agg) {
  __shared__ float orow[CH], rrow[CH], red[8];
  int row = blockIdx.x;
  int bs = row >> 4, t = row & 15;
  int b = bs / 3, s = bs % 3;
  const float* x = spf + ((size_t)(b * CT + t) * CS + s) * CH;
  const float* o = ob + (size_t)row * CH;
  for (int i = threadIdx.x; i < CH; i += 256) orow[i] = o[i];
  __syncthreads();
  const float* wto = ws_c + OFS_WTOT;
  for (int p = 0; p < 2; ++p) {
    int j = p * 256 + threadIdx.x;
    float acc = b_to[j];
    for (int c = 0; c < CH; ++c) acc += orow[c] * wto[c * CH + j];
    rrow[j] = acc + x[j];
  }
  __syncthreads();
  float part = rrow[threadIdx.x] + rrow[threadIdx.x + 256];
  for (int o2 = 32; o2; o2 >>= 1) part += __shfl_xor(part, o2);
  if ((threadIdx.x & 63) == 0) red[threadIdx.x >> 6] = part;
  __syncthreads();
  float mean = (red[0] + red[1] + red[2] + red[3]) * (1.f / CH);
  float d0 = rrow[threadIdx.x] - mean, d1 = rrow[threadIdx.x + 256] - mean;
  float p2 = d0 * d0 + d1 * d1;
  for (int o2 = 32; o2; o2 >>= 1) p2 += __shfl_xor(p2, o2);
  __syncthreads();
  if ((threadIdx.x & 63) == 0) red[(threadIdx.x >> 6) + 4] = p2;
  __syncthreads();
  float rstd = rsqrtf((red[4] + red[5] + red[6] + red[7]) * (1.f / CH) + 1e-5f);
  for (int p = 0; p < 2; ++p) {
    int j = p * 256 + threadIdx.x;
    float xt = (rrow[j] - mean) * rstd * g_lt[j] + b_lt[j];
    atomicAdd(&agg[(size_t)bs * CH + j], xt * (1.f / CT));
  }
}

// ================= launch =================
extern "C" void kernel_launch(void* const* d_in, const int* in_sizes, int n_in,
                              void* d_out, int out_size, void* d_ws, size_t ws_size,
                              hipStream_t stream) {
  (void)in_sizes; (void)n_in; (void)out_size; (void)ws_size;
  const float* visual = (const float*)d_in[0];
  const float* noise  = (const float*)d_in[1];
  const float* mu     = (const float*)d_in[2];
  const float* sigma  = (const float*)d_in[3];
  const float* w_in   = (const float*)d_in[4];
  const float* b_in   = (const float*)d_in[5];
  const float* g_lin  = (const float*)d_in[6];
  const float* b_lin  = (const float*)d_in[7];
  const float* w_m1p  = (const float*)d_in[8];
  const float* b_m1p  = (const float*)d_in[9];
  const float* w_m2p  = (const float*)d_in[10];
  const float* b_m2p  = (const float*)d_in[11];
  const float* w_q    = (const float*)d_in[12];
  const float* w_k    = (const float*)d_in[13];
  const float* w_v    = (const float*)d_in[14];
  const float* w_ih   = (const float*)d_in[15];
  const float* w_hh   = (const float*)d_in[16];
  const float* b_ih   = (const float*)d_in[17];
  const float* b_hh   = (const float*)d_in[18];
  const float* g_ls   = (const float*)d_in[19];
  const float* b_ls   = (const float*)d_in[20];
  const float* g_lm   = (const float*)d_in[21];
  const float* b_lm   = (const float*)d_in[22];
  const float* w_mlp1 = (const float*)d_in[23];
  const float* b_mlp1 = (const float*)d_in[24];
  const float* w_mlp2 = (const float*)d_in[25];
  const float* b_mlp2 = (const float*)d_in[26];
  const float* w_tq   = (const float*)d_in[27];
  const float* b_tq   = (const float*)d_in[28];
  const float* w_tk   = (const float*)d_in[29];
  const float* b_tk   = (const float*)d_in[30];
  const float* w_tv   = (const float*)d_in[31];
  const float* b_tv   = (const float*)d_in[32];
  const float* w_to   = (const float*)d_in[33];
  const float* b_to   = (const float*)d_in[34];
  const float* g_lt   = (const float*)d_in[35];
  const float* b_lt   = (const float*)d_in[36];

  float* ws  = (float*)d_ws;
  float* out = (float*)d_out;
  float* spf = out + 12288;
  float* att = out + 12288 + 196608;

  hipLaunchKernelGGL(k_init, dim3(48), dim3(256), 0, stream, noise, mu, sigma, ws, out);
  hipLaunchKernelGGL(k_transpose, dim3(16, 16, 4), dim3(256), 0, stream,
                     w_to, w_tq, w_tk, w_tv, ws);
  // Stage 1
  hipLaunchKernelGGL(k_p1, dim3(4, 256), dim3(256), 0, stream,
                     visual, w_in, b_in, ws + OFS_P1);
  hipLaunchKernelGGL(k_rowstats, dim3(CM / 4), dim3(256), 0, stream,
                     ws + OFS_P1, ws + OFS_ST);
  hipLaunchKernelGGL(k_m1, dim3(4, 256), dim3(256), 0, stream,
                     visual, w_m1p, b_m1p, ws + OFS_M1);
  hipLaunchKernelGGL(k_feats, dim3(4, 256), dim3(256), 0, stream,
                     ws + OFS_M1, w_m2p, b_m2p, ws + OFS_ST, g_lin, b_lin, ws + OFS_P1);
  hipLaunchKernelGGL(k_kv, dim3(8, 256), dim3(256), 0, stream,
                     ws + OFS_P1, w_k, w_v, ws + OFS_M1, ws + OFS_V);
  // Stage 2: phase-split scan v3 — read-once weights, 32-128 blocks, short chains
  for (int t = 0; t < CT; ++t) {
    for (int it = 0; it < NITER; ++it) {
      int lastit = (it == NITER - 1) ? 1 : 0;
      hipLaunchKernelGGL(ph_A,  dim3(128),   dim3(256), 0, stream, ws, w_q, w_hh, g_ls, b_ls, b_hh);
      hipLaunchKernelGGL(ph_B1, dim3(8, 8),  dim3(256), 0, stream, ws, att, t, lastit);
      hipLaunchKernelGGL(ph_B2, dim3(2, 24), dim3(256), 0, stream, ws, t);
      hipLaunchKernelGGL(ph_C,  dim3(64),    dim3(256), 0, stream, ws, w_ih, b_ih);
      hipLaunchKernelGGL(ph_D,  dim3(64),    dim3(256), 0, stream, ws, w_mlp1, g_lm, b_lm, b_mlp1);
      hipLaunchKernelGGL(ph_E,  dim3(32),    dim3(256), 0, stream, ws, w_mlp2, b_mlp2, spf, t, lastit);
    }
  }
  // Stage 3: temporal attention
  hipLaunchKernelGGL(k_tproj, dim3(384), dim3(256), 0, stream,
                     spf, ws, b_tq, b_tk, b_tv, ws + OFS_TQKV);
  hipLaunchKernelGGL(k_tattn, dim3(192), dim3(64), 0, stream,
                     ws + OFS_TQKV, ws + OFS_TO);
  hipLaunchKernelGGL(k_tout, dim3(384), dim3(256), 0, stream,
                     ws + OFS_TO, spf, ws, b_to, g_lt, b_lt, out);
}

// Round 9
// 6206.887 us; speedup vs baseline: 2.0604x; 1.0276x over previous
//
#include <hip/hip_runtime.h>
#include <math.h>

// ---------------- problem constants ----------------
#define CB 8
#define CT 16
#define CN 256
#define CD 1280
#define CH 512
#define CS 3
#define CM (CB*CT*CN)      // 32768 rows
#define CBS (CB*CS)        // 24
#define CH3 (3*CH)         // 1536
#define CH2 (2*CH)         // 1024
#define NITER 3

// ---------------- workspace layout (float offsets) ----------------
#define OFS_P1   0ULL                       // P1, later feats (in-place): CM*CH
#define OFS_M1   16777216ULL                // M1, later k_buf (overwrite): CM*CH
#define OFS_V    33554432ULL                // v buf (row-major): CM*CH
#define OFS_ST   50331648ULL                // rowstats: CM*2
#define OFS_WTOT 50397184ULL                // stage-3 transposes
#define OFS_WTQT (OFS_WTOT + 262144ULL)
#define OFS_WTKT (OFS_WTQT + 262144ULL)
#define OFS_WTVT (OFS_WTKT + 262144ULL)
#define OFS_SLOTS (OFS_WTVT + 262144ULL)    // 24*512
#define OFS_Q    (OFS_SLOTS + 12288ULL)     // 24*512
#define OFS_GH   (OFS_Q + 12288ULL)         // 24*1536
#define OFS_ATTN (OFS_GH + 36864ULL)        // 24*256
#define OFS_U    (OFS_ATTN + 6144ULL)       // 24*512
#define OFS_Z    (OFS_U + 12288ULL)         // (unused)
#define OFS_H    (OFS_Z + 32ULL)            // 24*512
#define OFS_Y    (OFS_H + 12288ULL)         // 24*1024
#define OFS_TQKV (OFS_Y + 24576ULL)         // 384*1536
#define OFS_TO   (OFS_TQKV + 589824ULL)     // 384*512

// ---------------- GEMM tiling ----------------
#define BM 128
#define BN 128
#define BK 16

// ================= init: slots0, zero agg =================
__global__ __launch_bounds__(256) void k_init(const float* __restrict__ noise,
                                              const float* __restrict__ mu,
                                              const float* __restrict__ sigma,
                                              float* __restrict__ ws,
                                              float* __restrict__ out) {
  int i = blockIdx.x * 256 + threadIdx.x;
  if (i < 12288) {
    int sj = i % 1536;  // (s,h) index into mu/sigma [1,3,512]
    ws[OFS_SLOTS + i] = mu[sj] + sigma[sj] * noise[i];
    out[i] = 0.0f;      // zero slots_agg accumulation region
  }
}

// ================= weight transposes (k-major) for stage-3 kernels =================
__global__ __launch_bounds__(256) void k_transpose(const float* __restrict__ w_to,
                                                   const float* __restrict__ w_tq,
                                                   const float* __restrict__ w_tk,
                                                   const float* __restrict__ w_tv,
                                                   float* __restrict__ ws) {
  const float* src; float* dst;
  switch (blockIdx.z) {
    case 0: src = w_to; dst = ws + OFS_WTOT; break;
    case 1: src = w_tq; dst = ws + OFS_WTQT; break;
    case 2: src = w_tk; dst = ws + OFS_WTKT; break;
    default: src = w_tv; dst = ws + OFS_WTVT; break;
  }
  const int R = 512, C = 512;
  int r0 = blockIdx.y * 32, c0 = blockIdx.x * 32;
  __shared__ float tile[32][33];
  int tx = threadIdx.x & 31, ty = threadIdx.x >> 5;  // 32 x 8
  for (int i = ty; i < 32; i += 8)
    tile[i][tx] = src[(size_t)(r0 + i) * C + c0 + tx];
  __syncthreads();
  for (int i = ty; i < 32; i += 8)
    dst[(size_t)(c0 + i) * R + r0 + tx] = tile[tx][i];
}

// ================= GEMM 1: P1 = visual @ w_in.T + b_in (BK=16, float4 staging) =================
__global__ __launch_bounds__(256) void k_p1(const float* __restrict__ A,
                                            const float* __restrict__ W,
                                            const float* __restrict__ bias,
                                            float* __restrict__ Cout) {
  __shared__ float As[BK][BM + 4];
  __shared__ float Bs[BK][BN + 4];
  const int tid = threadIdx.x;
  const int m0 = blockIdx.y * BM;
  const int n0 = blockIdx.x * BN;
  const int tx = tid & 15, ty = tid >> 4;
  const int lr = tid >> 2, lc = (tid & 3) * 4;   // 64 rows x 4 float4-cols
  float acc[8][8];
#pragma unroll
  for (int i = 0; i < 8; ++i)
#pragma unroll
    for (int j = 0; j < 8; ++j) acc[i][j] = 0.f;

  for (int kb = 0; kb < CD; kb += BK) {
    {
      float4 a0 = *(const float4*)&A[(size_t)(m0 + lr) * CD + kb + lc];
      float4 a1 = *(const float4*)&A[(size_t)(m0 + lr + 64) * CD + kb + lc];
      float4 b0 = *(const float4*)&W[(size_t)(n0 + lr) * CD + kb + lc];
      float4 b1 = *(const float4*)&W[(size_t)(n0 + lr + 64) * CD + kb + lc];
      As[lc + 0][lr] = a0.x; As[lc + 1][lr] = a0.y; As[lc + 2][lr] = a0.z; As[lc + 3][lr] = a0.w;
      As[lc + 0][lr + 64] = a1.x; As[lc + 1][lr + 64] = a1.y; As[lc + 2][lr + 64] = a1.z; As[lc + 3][lr + 64] = a1.w;
      Bs[lc + 0][lr] = b0.x; Bs[lc + 1][lr] = b0.y; Bs[lc + 2][lr] = b0.z; Bs[lc + 3][lr] = b0.w;
      Bs[lc + 0][lr + 64] = b1.x; Bs[lc + 1][lr + 64] = b1.y; Bs[lc + 2][lr + 64] = b1.z; Bs[lc + 3][lr + 64] = b1.w;
    }
    __syncthreads();
#pragma unroll
    for (int kk = 0; kk < BK; ++kk) {
      float av[8], bv[8];
      *(float4*)&av[0] = *(const float4*)&As[kk][ty * 8];
      *(float4*)&av[4] = *(const float4*)&As[kk][ty * 8 + 4];
      *(float4*)&bv[0] = *(const float4*)&Bs[kk][tx * 8];
      *(float4*)&bv[4] = *(const float4*)&Bs[kk][tx * 8 + 4];
#pragma unroll
      for (int i = 0; i < 8; ++i)
#pragma unroll
        for (int j = 0; j < 8; ++j) acc[i][j] += av[i] * bv[j];
    }
    __syncthreads();
  }
#pragma unroll
  for (int i = 0; i < 8; ++i) {
    int m = m0 + ty * 8 + i;
#pragma unroll
    for (int j = 0; j < 8; ++j) {
      int n = n0 + tx * 8 + j;
      Cout[(size_t)m * CH + n] = acc[i][j] + bias[n];
    }
  }
}

// ================= GEMM 2: M1 = relu(motion @ w_m1p.T + b_m1p) =================
__global__ __launch_bounds__(256) void k_m1(const float* __restrict__ A,
                                            const float* __restrict__ W,
                                            const float* __restrict__ bias,
                                            float* __restrict__ Cout) {
  __shared__ float As[BK][BM + 4];
  __shared__ float Bs[BK][BN + 4];
  const int tid = threadIdx.x;
  const int m0 = blockIdx.y * BM;
  const int n0 = blockIdx.x * BN;
  const int tx = tid & 15, ty = tid >> 4;
  const int lr = tid >> 2, lc = (tid & 3) * 4;
  const int frame = (m0 >> 8);         // (b*16 + t)
  const int tfrm = frame & 15;
  float acc[8][8];
#pragma unroll
  for (int i = 0; i < 8; ++i)
#pragma unroll
    for (int j = 0; j < 8; ++j) acc[i][j] = 0.f;

  for (int kb = 0; kb < CD; kb += BK) {
    {
      float4 a0 = make_float4(0.f, 0.f, 0.f, 0.f), a1 = a0;
      if (tfrm < 15) {
        float4 c0 = *(const float4*)&A[(size_t)(m0 + lr) * CD + kb + lc];
        float4 n0v = *(const float4*)&A[(size_t)(m0 + lr + 256) * CD + kb + lc];
        a0 = make_float4(n0v.x - c0.x, n0v.y - c0.y, n0v.z - c0.z, n0v.w - c0.w);
        float4 c1 = *(const float4*)&A[(size_t)(m0 + lr + 64) * CD + kb + lc];
        float4 n1v = *(const float4*)&A[(size_t)(m0 + lr + 320) * CD + kb + lc];
        a1 = make_float4(n1v.x - c1.x, n1v.y - c1.y, n1v.z - c1.z, n1v.w - c1.w);
      }
      float4 b0 = *(const float4*)&W[(size_t)(n0 + lr) * CD + kb + lc];
      float4 b1 = *(const float4*)&W[(size_t)(n0 + lr + 64) * CD + kb + lc];
      As[lc + 0][lr] = a0.x; As[lc + 1][lr] = a0.y; As[lc + 2][lr] = a0.z; As[lc + 3][lr] = a0.w;
      As[lc + 0][lr + 64] = a1.x; As[lc + 1][lr + 64] = a1.y; As[lc + 2][lr + 64] = a1.z; As[lc + 3][lr + 64] = a1.w;
      Bs[lc + 0][lr] = b0.x; Bs[lc + 1][lr] = b0.y; Bs[lc + 2][lr] = b0.z; Bs[lc + 3][lr] = b0.w;
      Bs[lc + 0][lr + 64] = b1.x; Bs[lc + 1][lr + 64] = b1.y; Bs[lc + 2][lr + 64] = b1.z; Bs[lc + 3][lr + 64] = b1.w;
    }
    __syncthreads();
#pragma unroll
    for (int kk = 0; kk < BK; ++kk) {
      float av[8], bv[8];
      *(float4*)&av[0] = *(const float4*)&As[kk][ty * 8];
      *(float4*)&av[4] = *(const float4*)&As[kk][ty * 8 + 4];
      *(float4*)&bv[0] = *(const float4*)&Bs[kk][tx * 8];
      *(float4*)&bv[4] = *(const float4*)&Bs[kk][tx * 8 + 4];
#pragma unroll
      for (int i = 0; i < 8; ++i)
#pragma unroll
        for (int j = 0; j < 8; ++j) acc[i][j] += av[i] * bv[j];
    }
    __syncthreads();
  }
#pragma unroll
  for (int i = 0; i < 8; ++i) {
    int m = m0 + ty * 8 + i;
#pragma unroll
    for (int j = 0; j < 8; ++j) {
      int n = n0 + tx * 8 + j;
      Cout[(size_t)m * CH + n] = fmaxf(acc[i][j] + bias[n], 0.f);
    }
  }
}

// ================= row stats of P1 for LN =================
__global__ __launch_bounds__(256) void k_rowstats(const float* __restrict__ P1,
                                                  float* __restrict__ st) {
  int row = blockIdx.x * 4 + (threadIdx.x >> 6);
  int lane = threadIdx.x & 63;
  const float* r = P1 + (size_t)row * CH;
  float4 x0 = *(const float4*)&r[lane * 8];
  float4 x1 = *(const float4*)&r[lane * 8 + 4];
  float s = x0.x + x0.y + x0.z + x0.w + x1.x + x1.y + x1.z + x1.w;
  for (int o = 32; o; o >>= 1) s += __shfl_xor(s, o);
  float mean = s * (1.f / CH);
  float d, s2 = 0.f;
  d = x0.x - mean; s2 += d * d; d = x0.y - mean; s2 += d * d;
  d = x0.z - mean; s2 += d * d; d = x0.w - mean; s2 += d * d;
  d = x1.x - mean; s2 += d * d; d = x1.y - mean; s2 += d * d;
  d = x1.z - mean; s2 += d * d; d = x1.w - mean; s2 += d * d;
  for (int o = 32; o; o >>= 1) s2 += __shfl_xor(s2, o);
  if (lane == 0) {
    st[2 * row] = mean;
    st[2 * row + 1] = rsqrtf(s2 * (1.f / CH) + 1e-5f);
  }
}

// ================= GEMM 3: feats = LN(P1)*g+b + 0.5*(M1 @ w_m2p.T + b_m2p), in-place =================
__global__ __launch_bounds__(256) void k_feats(const float* __restrict__ A,  // M1
                                               const float* __restrict__ W,  // w_m2p
                                               const float* __restrict__ bias,
                                               const float* __restrict__ st,
                                               const float* __restrict__ g_ln,
                                               const float* __restrict__ b_ln,
                                               float* __restrict__ P1inout) {
  __shared__ float As[BK][BM + 4];
  __shared__ float Bs[BK][BN + 4];
  const int tid = threadIdx.x;
  const int m0 = blockIdx.y * BM;
  const int n0 = blockIdx.x * BN;
  const int tx = tid & 15, ty = tid >> 4;
  const int lr = tid >> 2, lc = (tid & 3) * 4;
  float acc[8][8];
#pragma unroll
  for (int i = 0; i < 8; ++i)
#pragma unroll
    for (int j = 0; j < 8; ++j) acc[i][j] = 0.f;

  for (int kb = 0; kb < CH; kb += BK) {
    {
      float4 a0 = *(const float4*)&A[(size_t)(m0 + lr) * CH + kb + lc];
      float4 a1 = *(const float4*)&A[(size_t)(m0 + lr + 64) * CH + kb + lc];
      float4 b0 = *(const float4*)&W[(size_t)(n0 + lr) * CH + kb + lc];
      float4 b1 = *(const float4*)&W[(size_t)(n0 + lr + 64) * CH + kb + lc];
      As[lc + 0][lr] = a0.x; As[lc + 1][lr] = a0.y; As[lc + 2][lr] = a0.z; As[lc + 3][lr] = a0.w;
      As[lc + 0][lr + 64] = a1.x; As[lc + 1][lr + 64] = a1.y; As[lc + 2][lr + 64] = a1.z; As[lc + 3][lr + 64] = a1.w;
      Bs[lc + 0][lr] = b0.x; Bs[lc + 1][lr] = b0.y; Bs[lc + 2][lr] = b0.z; Bs[lc + 3][lr] = b0.w;
      Bs[lc + 0][lr + 64] = b1.x; Bs[lc + 1][lr + 64] = b1.y; Bs[lc + 2][lr + 64] = b1.z; Bs[lc + 3][lr + 64] = b1.w;
    }
    __syncthreads();
#pragma unroll
    for (int kk = 0; kk < BK; ++kk) {
      float av[8], bv[8];
      *(float4*)&av[0] = *(const float4*)&As[kk][ty * 8];
      *(float4*)&av[4] = *(const float4*)&As[kk][ty * 8 + 4];
      *(float4*)&bv[0] = *(const float4*)&Bs[kk][tx * 8];
      *(float4*)&bv[4] = *(const float4*)&Bs[kk][tx * 8 + 4];
#pragma unroll
      for (int i = 0; i < 8; ++i)
#pragma unroll
        for (int j = 0; j < 8; ++j) acc[i][j] += av[i] * bv[j];
    }
    __syncthreads();
  }
#pragma unroll
  for (int i = 0; i < 8; ++i) {
    int m = m0 + ty * 8 + i;
    float mean = st[2 * m], rstd = st[2 * m + 1];
#pragma unroll
    for (int j = 0; j < 8; ++j) {
      int n = n0 + tx * 8 + j;
      size_t idx = (size_t)m * CH + n;
      float p1v = P1inout[idx];
      float v = (p1v - mean) * rstd * g_ln[n] + b_ln[n] + 0.5f * (acc[i][j] + bias[n]);
      P1inout[idx] = v;
    }
  }
}

// ================= GEMM 4: k | v (both row-major) = feats @ [w_k; w_v].T =================
__global__ __launch_bounds__(256) void k_kv(const float* __restrict__ A,  // feats
                                            const float* __restrict__ Wk,
                                            const float* __restrict__ Wv,
                                            float* __restrict__ kbuf,
                                            float* __restrict__ vbuf) {
  __shared__ float As[BK][BM + 4];
  __shared__ float Bs[BK][BN + 4];
  const int tid = threadIdx.x;
  const int m0 = blockIdx.y * BM;
  const int n0 = blockIdx.x * BN;  // 0..1023
  const int tx = tid & 15, ty = tid >> 4;
  const int lr = tid >> 2, lc = (tid & 3) * 4;
  const bool khalf = (n0 < 512);
  const float* W = khalf ? (Wk + (size_t)n0 * CH) : (Wv + (size_t)(n0 - 512) * CH);
  float* Out = khalf ? kbuf : vbuf;
  const int nbase = khalf ? n0 : (n0 - 512);
  float acc[8][8];
#pragma unroll
  for (int i = 0; i < 8; ++i)
#pragma unroll
    for (int j = 0; j < 8; ++j) acc[i][j] = 0.f;

  for (int kb = 0; kb < CH; kb += BK) {
    {
      float4 a0 = *(const float4*)&A[(size_t)(m0 + lr) * CH + kb + lc];
      float4 a1 = *(const float4*)&A[(size_t)(m0 + lr + 64) * CH + kb + lc];
      float4 b0 = *(const float4*)&W[(size_t)lr * CH + kb + lc];
      float4 b1 = *(const float4*)&W[(size_t)(lr + 64) * CH + kb + lc];
      As[lc + 0][lr] = a0.x; As[lc + 1][lr] = a0.y; As[lc + 2][lr] = a0.z; As[lc + 3][lr] = a0.w;
      As[lc + 0][lr + 64] = a1.x; As[lc + 1][lr + 64] = a1.y; As[lc + 2][lr + 64] = a1.z; As[lc + 3][lr + 64] = a1.w;
      Bs[lc + 0][lr] = b0.x; Bs[lc + 1][lr] = b0.y; Bs[lc + 2][lr] = b0.z; Bs[lc + 3][lr] = b0.w;
      Bs[lc + 0][lr + 64] = b1.x; Bs[lc + 1][lr + 64] = b1.y; Bs[lc + 2][lr + 64] = b1.z; Bs[lc + 3][lr + 64] = b1.w;
    }
    __syncthreads();
#pragma unroll
    for (int kk = 0; kk < BK; ++kk) {
      float av[8], bv[8];
      *(float4*)&av[0] = *(const float4*)&As[kk][ty * 8];
      *(float4*)&av[4] = *(const float4*)&As[kk][ty * 8 + 4];
      *(float4*)&bv[0] = *(const float4*)&Bs[kk][tx * 8];
      *(float4*)&bv[4] = *(const float4*)&Bs[kk][tx * 8 + 4];
#pragma unroll
      for (int i = 0; i < 8; ++i)
#pragma unroll
        for (int j = 0; j < 8; ++j) acc[i][j] += av[i] * bv[j];
    }
    __syncthreads();
  }
#pragma unroll
  for (int i = 0; i < 8; ++i) {
    int m = m0 + ty * 8 + i;
#pragma unroll
    for (int j = 0; j < 8; ++j) {
      int n = nbase + tx * 8 + j;
      Out[(size_t)m * CH + n] = acc[i][j];
    }
  }
}

// ============================================================================
// Slot-attention scan, phase-split v3 (unchanged from round 8).
// ============================================================================

// ---- Phase A: q = LN(slots)@w_q.T (bx<32) ; gh = slots@w_hh.T + b_hh (bx 32..127) ----
__global__ __launch_bounds__(256) void ph_A(float* __restrict__ ws,
                                            const float* __restrict__ w_q_g,
                                            const float* __restrict__ w_hh_g,
                                            const float* __restrict__ g_ls,
                                            const float* __restrict__ b_ls,
                                            const float* __restrict__ b_hh) {
  __shared__ float act[CBS * CH];        // 48 KB
  __shared__ float part[384][17];        // 25.5 KB, padded for reduce
  __shared__ float lm[CBS], lr[CBS];
  const int bx = blockIdx.x;             // 0..127
  const int tid = threadIdx.x;
  const bool isq = (bx < 32);
  const float* slots = ws + OFS_SLOTS;
  for (int i = tid; i < CBS * CH / 4; i += 256)
    ((float4*)act)[i] = ((const float4*)slots)[i];
  __syncthreads();
  if (isq) {
    int wv = tid >> 6, lane = tid & 63;
    for (int rr = 0; rr < 6; ++rr) {
      int r = wv * 6 + rr;
      const float* row = act + r * CH;
      float s = 0.f;
#pragma unroll
      for (int i = 0; i < 8; ++i) s += row[lane + 64 * i];
      for (int o = 32; o; o >>= 1) s += __shfl_xor(s, o);
      float mean = s * (1.f / CH);
      float s2 = 0.f;
#pragma unroll
      for (int i = 0; i < 8; ++i) { float d = row[lane + 64 * i] - mean; s2 += d * d; }
      for (int o = 32; o; o >>= 1) s2 += __shfl_xor(s2, o);
      if (lane == 0) { lm[r] = mean; lr[r] = rsqrtf(s2 * (1.f / CH) + 1e-5f); }
    }
    __syncthreads();
    for (int i = tid; i < CBS * CH; i += 256) {
      int r = i >> 9, k = i & 511;
      act[i] = (act[i] - lm[r]) * lr[r] * g_ls[k] + b_ls[k];
    }
    __syncthreads();
  }
  const int cl = tid & 15, ks = tid >> 4;          // 16 cols x 16 k-slices(32)
  const int c = (isq ? bx : (bx - 32)) * 16 + cl;
  const float* wrow = (isq ? w_q_g : w_hh_g) + (size_t)c * CH + ks * 32;
  float acc[CBS];
#pragma unroll
  for (int r = 0; r < CBS; ++r) acc[r] = 0.f;
#pragma unroll
  for (int j = 0; j < 8; ++j) {
    float4 w4 = *(const float4*)&wrow[j * 4];
    const float* ab = act + ks * 32 + j * 4;
#pragma unroll
    for (int r = 0; r < CBS; ++r) {
      float4 a4 = *(const float4*)&ab[r * CH];
      acc[r] += a4.x * w4.x + a4.y * w4.y + a4.z * w4.z + a4.w * w4.w;
    }
  }
#pragma unroll
  for (int r = 0; r < CBS; ++r) part[cl * CBS + r][ks] = acc[r];
  __syncthreads();
  for (int o = tid; o < 384; o += 256) {
    float s = 0.f;
#pragma unroll
    for (int q2 = 0; q2 < 16; ++q2) s += part[o][q2];
    int cl2 = o / CBS, r = o - cl2 * CBS;
    if (isq) {
      ws[OFS_Q + (size_t)r * CH + bx * 16 + cl2] = s;
    } else {
      int cg = (bx - 32) * 16 + cl2;
      ws[OFS_GH + (size_t)r * CH3 + cg] = s + b_hh[cg];
    }
  }
}

// ---- Phase B1: logits -> softmax over slots -> attn. grid (8, 8) ----
__global__ __launch_bounds__(256) void ph_B1(float* __restrict__ ws,
                                             float* __restrict__ att,
                                             int t, int lastit) {
  const int b = blockIdx.y;        // 0..7
  const int chunk = blockIdx.x;    // 0..7 (32 n each)
  const int wv = threadIdx.x >> 6, lane = threadIdx.x & 63;
  const float* qb = ws + OFS_Q + (size_t)b * 3 * CH;
  const float* kbuf = ws + OFS_M1;
  float* attnb = ws + OFS_ATTN;
  const float scale = 0.04419417382415922f;  // 512^-0.5
#pragma unroll
  for (int i = 0; i < 8; ++i) {
    int n = chunk * 32 + wv * 8 + i;
    const float* krow = kbuf + ((size_t)((b * CT + t) * CN + n)) * CH;
    float p0 = 0.f, p1 = 0.f, p2 = 0.f;
#pragma unroll
    for (int u = 0; u < 2; ++u) {
      int k = lane * 8 + u * 4;
      float4 kk = *(const float4*)&krow[k];
      float4 a0 = *(const float4*)&qb[k];
      float4 a1 = *(const float4*)&qb[CH + k];
      float4 a2 = *(const float4*)&qb[2 * CH + k];
      p0 += a0.x * kk.x + a0.y * kk.y + a0.z * kk.z + a0.w * kk.w;
      p1 += a1.x * kk.x + a1.y * kk.y + a1.z * kk.z + a1.w * kk.w;
      p2 += a2.x * kk.x + a2.y * kk.y + a2.z * kk.z + a2.w * kk.w;
    }
    for (int o = 32; o; o >>= 1) {
      p0 += __shfl_xor(p0, o); p1 += __shfl_xor(p1, o); p2 += __shfl_xor(p2, o);
    }
    p0 *= scale; p1 *= scale; p2 *= scale;
    float mx = fmaxf(p0, fmaxf(p1, p2));
    float e0 = expf(p0 - mx), e1 = expf(p1 - mx), e2 = expf(p2 - mx);
    float inv = 1.f / (e0 + e1 + e2);
    if (lane < 3) {
      float a = (lane == 0 ? e0 : (lane == 1 ? e1 : e2)) * inv;
      attnb[(b * 3 + lane) * CN + n] = a;
      if (lastit)
        att[((size_t)(b * CT + t) * CS + lane) * CN + n] = a;
    }
  }
}

// ---- Phase B2: U = (attn @ v) / Z. grid (2, 24) ----
__global__ __launch_bounds__(256) void ph_B2(float* __restrict__ ws, int t) {
  const int r = blockIdx.y;        // 0..23
  const int chunk = blockIdx.x;    // 0..1
  const int b = r / 3;
  const int tid = threadIdx.x;
  __shared__ float arow[CN], red[4];
  __shared__ float iz;
  const float* attnb = ws + OFS_ATTN + (size_t)r * CN;
  float a = attnb[tid];
  arow[tid] = a;
  float z = a;
  for (int o = 32; o; o >>= 1) z += __shfl_xor(z, o);
  if ((tid & 63) == 0) red[tid >> 6] = z;
  __syncthreads();
  if (tid == 0) iz = 1.f / (red[0] + red[1] + red[2] + red[3] + 1e-8f);
  __syncthreads();
  int c = chunk * 256 + tid;
  const float* v = ws + OFS_V + ((size_t)(b * CT + t) * CN) * CH + c;
  float a0 = 0.f, a1 = 0.f, a2 = 0.f, a3 = 0.f;
  for (int n = 0; n < CN; n += 4) {
    a0 += arow[n]     * v[(size_t)(n)     * CH];
    a1 += arow[n + 1] * v[(size_t)(n + 1) * CH];
    a2 += arow[n + 2] * v[(size_t)(n + 2) * CH];
    a3 += arow[n + 3] * v[(size_t)(n + 3) * CH];
  }
  ws[OFS_U + (size_t)r * CH + c] = (a0 + a1 + a2 + a3) * iz;
}

// ---- Phase C: gi = U@w_ih.T + b_ih (24 cols/block) ; GRU -> h. grid 64 ----
__global__ __launch_bounds__(256) void ph_C(float* __restrict__ ws,
                                            const float* __restrict__ w_ih_g,
                                            const float* __restrict__ b_ih) {
  __shared__ float act[CBS * CH];        // 48 KB (U)
  __shared__ float part[576][9];         // 20.3 KB
  __shared__ float gil[576];             // 2.3 KB
  const int bx = blockIdx.x;             // 0..63 -> j0 = bx*8
  const int tid = threadIdx.x;
  const float* U = ws + OFS_U;
  for (int i = tid; i < CBS * CH / 4; i += 256)
    ((float4*)act)[i] = ((const float4*)U)[i];
  __syncthreads();
  if (tid < 192) {
    const int cidx = tid % 24, ks = tid / 24;   // 24 cols x 8 k-slices(64)
    const int gate = cidx >> 3, jl = cidx & 7;
    const int col = gate * 512 + bx * 8 + jl;
    const float* wrow = w_ih_g + (size_t)col * CH + ks * 64;
    float acc[CBS];
#pragma unroll
    for (int r = 0; r < CBS; ++r) acc[r] = 0.f;
#pragma unroll
    for (int j = 0; j < 16; ++j) {
      float4 w4 = *(const float4*)&wrow[j * 4];
      const float* ab = act + ks * 64 + j * 4;
#pragma unroll
      for (int r = 0; r < CBS; ++r) {
        float4 a4 = *(const float4*)&ab[r * CH];
        acc[r] += a4.x * w4.x + a4.y * w4.y + a4.z * w4.z + a4.w * w4.w;
      }
    }
#pragma unroll
    for (int r = 0; r < CBS; ++r) part[cidx * CBS + r][ks] = acc[r];
  }
  __syncthreads();
  for (int o = tid; o < 576; o += 256) {
    float s = 0.f;
#pragma unroll
    for (int q2 = 0; q2 < 8; ++q2) s += part[o][q2];
    int cidx = o / CBS;
    int gate = cidx >> 3, jl = cidx & 7;
    gil[o] = s + b_ih[gate * 512 + bx * 8 + jl];
  }
  __syncthreads();
  if (tid < 192) {
    const int r = tid >> 3, jl = tid & 7;
    const int j = bx * 8 + jl;
    float ir  = gil[(jl)      * CBS + r];
    float iz2 = gil[(8 + jl)  * CBS + r];
    float inn = gil[(16 + jl) * CBS + r];
    const float* gh = ws + OFS_GH;
    float hr = gh[(size_t)r * CH3 + j];
    float hz = gh[(size_t)r * CH3 + CH + j];
    float hn = gh[(size_t)r * CH3 + 2 * CH + j];
    float rr = 1.f / (1.f + expf(-(ir + hr)));
    float zz = 1.f / (1.f + expf(-(iz2 + hz)));
    float nn = tanhf(inn + rr * hn);
    float sl = ws[OFS_SLOTS + (size_t)r * CH + j];
    ws[OFS_H + (size_t)r * CH + j] = (1.f - zz) * nn + zz * sl;
  }
}

// ---- Phase D: y = gelu(LN(h)@w_mlp1.T + b_m1). grid 64 ----
__global__ __launch_bounds__(256) void ph_D(float* __restrict__ ws,
                                            const float* __restrict__ w_m1_g,
                                            const float* __restrict__ g_lm,
                                            const float* __restrict__ b_lm,
                                            const float* __restrict__ b_m1) {
  __shared__ float act[CBS * CH];        // 48 KB
  __shared__ float part[384][17];        // 25.5 KB
  __shared__ float lm[CBS], lr[CBS];
  const int bx = blockIdx.x;             // 0..63 -> cols bx*16..+16 of 1024
  const int tid = threadIdx.x;
  const float* hb = ws + OFS_H;
  for (int i = tid; i < CBS * CH / 4; i += 256)
    ((float4*)act)[i] = ((const float4*)hb)[i];
  __syncthreads();
  {
    int wv = tid >> 6, lane = tid & 63;
    for (int rr = 0; rr < 6; ++rr) {
      int r = wv * 6 + rr;
      const float* row = act + r * CH;
      float s = 0.f;
#pragma unroll
      for (int i = 0; i < 8; ++i) s += row[lane + 64 * i];
      for (int o = 32; o; o >>= 1) s += __shfl_xor(s, o);
      float mean = s * (1.f / CH);
      float s2 = 0.f;
#pragma unroll
      for (int i = 0; i < 8; ++i) { float d = row[lane + 64 * i] - mean; s2 += d * d; }
      for (int o = 32; o; o >>= 1) s2 += __shfl_xor(s2, o);
      if (lane == 0) { lm[r] = mean; lr[r] = rsqrtf(s2 * (1.f / CH) + 1e-5f); }
    }
  }
  __syncthreads();
  for (int i = tid; i < CBS * CH; i += 256) {
    int r = i >> 9, k = i & 511;
    act[i] = (act[i] - lm[r]) * lr[r] * g_lm[k] + b_lm[k];
  }
  __syncthreads();
  const int cl = tid & 15, ks = tid >> 4;
  const int c = bx * 16 + cl;
  const float* wrow = w_m1_g + (size_t)c * CH + ks * 32;
  float acc[CBS];
#pragma unroll
  for (int r = 0; r < CBS; ++r) acc[r] = 0.f;
#pragma unroll
  for (int j = 0; j < 8; ++j) {
    float4 w4 = *(const float4*)&wrow[j * 4];
    const float* ab = act + ks * 32 + j * 4;
#pragma unroll
    for (int r = 0; r < CBS; ++r) {
      float4 a4 = *(const float4*)&ab[r * CH];
      acc[r] += a4.x * w4.x + a4.y * w4.y + a4.z * w4.z + a4.w * w4.w;
    }
  }
#pragma unroll
  for (int r = 0; r < CBS; ++r) part[cl * CBS + r][ks] = acc[r];
  __syncthreads();
  for (int o = tid; o < 384; o += 256) {
    float s = 0.f;
#pragma unroll
    for (int q2 = 0; q2 < 16; ++q2) s += part[o][q2];
    int cl2 = o / CBS, r = o - cl2 * CBS;
    int c2 = bx * 16 + cl2;
    float x = s + b_m1[c2];
    ws[OFS_Y + (size_t)r * CH2 + c2] = 0.5f * x * (1.f + erff(x * 0.70710678118654752f));
  }
}

// ---- Phase E: slots' = h + y@w_mlp2.T + b_m2. grid 32 ----
__global__ __launch_bounds__(256) void ph_E(float* __restrict__ ws,
                                            const float* __restrict__ w_m2_g,
                                            const float* __restrict__ b_m2,
                                            float* __restrict__ spf,
                                            int t, int lastit) {
  __shared__ float act[CBS * CH2];       // 96 KB (y)
  __shared__ float part[384][17];        // 25.5 KB -> 121.5 KB total
  const int bx = blockIdx.x;             // 0..31 -> cols bx*16..+16 of 512
  const int tid = threadIdx.x;
  const float* yb = ws + OFS_Y;
  for (int i = tid; i < CBS * CH2 / 4; i += 256)
    ((float4*)act)[i] = ((const float4*)yb)[i];
  __syncthreads();
  const int cl = tid & 15, ks = tid >> 4;   // 16 cols x 16 k-slices(64)
  const int c = bx * 16 + cl;
  const float* wrow = w_m2_g + (size_t)c * CH2 + ks * 64;
  float acc[CBS];
#pragma unroll
  for (int r = 0; r < CBS; ++r) acc[r] = 0.f;
#pragma unroll
  for (int j = 0; j < 16; ++j) {
    float4 w4 = *(const float4*)&wrow[j * 4];
    const float* ab = act + ks * 64 + j * 4;
#pragma unroll
    for (int r = 0; r < CBS; ++r) {
      float4 a4 = *(const float4*)&ab[r * CH2];
      acc[r] += a4.x * w4.x + a4.y * w4.y + a4.z * w4.z + a4.w * w4.w;
    }
  }
#pragma unroll
  for (int r = 0; r < CBS; ++r) part[cl * CBS + r][ks] = acc[r];
  __syncthreads();
  for (int o = tid; o < 384; o += 256) {
    float s = 0.f;
#pragma unroll
    for (int q2 = 0; q2 < 16; ++q2) s += part[o][q2];
    int cl2 = o / CBS, r = o - cl2 * CBS;
    int c2 = bx * 16 + cl2;
    float sn = ws[OFS_H + (size_t)r * CH + c2] + s + b_m2[c2];
    ws[OFS_SLOTS + (size_t)r * CH + c2] = sn;
    if (lastit) {
      int b = r / 3, s5 = r % 3;
      spf[((size_t)(b * CT + t) * CS + s5) * CH + c2] = sn;
    }
  }
}

// ================= temporal attention: qkv projection =================
__global__ __launch_bounds__(256) void k_tproj(const float* __restrict__ spf,
                                               const float* __restrict__ ws_c,
                                               const float* __restrict__ b_tq,
                                               const float* __restrict__ b_tk,
                                               const float* __restrict__ b_tv,
                                               float* __restrict__ tqkv) {
  __shared__ float xr[CH];
  int row = blockIdx.x;  // bs*16 + t
  int bs = row >> 4, t = row & 15;
  int b = bs / 3, s = bs % 3;
  const float* x = spf + ((size_t)(b * CT + t) * CS + s) * CH;
  for (int i = threadIdx.x; i < CH; i += 256) xr[i] = x[i];
  __syncthreads();
  for (int p = 0; p < 6; ++p) {
    int j = p * 256 + threadIdx.x;
    const float* wT; const float* bb; int jj;
    if (j < 512)      { wT = ws_c + OFS_WTQT; bb = b_tq; jj = j; }
    else if (j < 1024){ wT = ws_c + OFS_WTKT; bb = b_tk; jj = j - 512; }
    else              { wT = ws_c + OFS_WTVT; bb = b_tv; jj = j - 1024; }
    float acc = bb[jj];
    for (int h = 0; h < CH; ++h) acc += xr[h] * wT[h * CH + jj];
    tqkv[(size_t)row * CH3 + j] = acc;
  }
}

// ================= temporal attention: per (track, head) =================
__global__ __launch_bounds__(64) void k_tattn(const float* __restrict__ tqkv,
                                              float* __restrict__ ob) {
  __shared__ float qs[16][68], ks[16][68], vs[16][68], sc[16][20];
  int bs = blockIdx.x >> 3, hh = blockIdx.x & 7;
  int lane = threadIdx.x;
  for (int i = 0; i < 16; ++i) {
    const float* base = tqkv + (size_t)(bs * 16 + i) * CH3 + hh * 64;
    qs[i][lane] = base[lane];
    ks[i][lane] = base[512 + lane];
    vs[i][lane] = base[1024 + lane];
  }
  __syncthreads();
  for (int u = 0; u < 4; ++u) {
    int ee = u * 64 + lane;
    int i = ee >> 4, j = ee & 15;
    float acc = 0.f;
    for (int d = 0; d < 64; ++d) acc += qs[i][d] * ks[j][d];
    sc[i][j] = acc * 0.125f;  // 1/sqrt(64)
  }
  __syncthreads();
  if (lane < 16) {
    float mx = -1e30f;
    for (int j = 0; j < 16; ++j) mx = fmaxf(mx, sc[lane][j]);
    float sum = 0.f;
    for (int j = 0; j < 16; ++j) { float ev = expf(sc[lane][j] - mx); sc[lane][j] = ev; sum += ev; }
    float inv = 1.f / sum;
    for (int j = 0; j < 16; ++j) sc[lane][j] *= inv;
  }
  __syncthreads();
  for (int i = 0; i < 16; ++i) {
    float acc = 0.f;
    for (int j = 0; j < 16; ++j) acc += sc[i][j] * vs[j][lane];
    ob[(size_t)(bs * 16 + i) * CH + hh * 64 + lane] = acc;
  }
}

// ================= temporal out-proj + residual + LN + mean =================
__global__ __launch_bounds__(256) void k_tout(const float* __restrict__ ob,
                                              const float* __restrict__ spf,
                                              const float* __restrict__ ws_c,
                                              const float* __restrict__ b_to,
                                              const float* __restrict__ g_lt,
                                              const float* __restrict__ b_lt,
                                              float* __restrict__ agg) {
  __shared__ float orow[CH], rrow[CH], red[8];
  int row = blockIdx.x;
  int bs = row >> 4, t = row & 15;
  int b = bs / 3, s = bs % 3;
  const float* x = spf + ((size_t)(b * CT + t) * CS + s) * CH;
  const float* o = ob + (size_t)row * CH;
  for (int i = threadIdx.x; i < CH; i += 256) orow[i] = o[i];
  __syncthreads();
  const float* wto = ws_c + OFS_WTOT;
  for (int p = 0; p < 2; ++p) {
    int j = p * 256 + threadIdx.x;
    float acc = b_to[j];
    for (int c = 0; c < CH; ++c) acc += orow[c] * wto[c * CH + j];
    rrow[j] = acc + x[j];
  }
  __syncthreads();
  float part = rrow[threadIdx.x] + rrow[threadIdx.x + 256];
  for (int o2 = 32; o2; o2 >>= 1) part += __shfl_xor(part, o2);
  if ((threadIdx.x & 63) == 0) red[threadIdx.x >> 6] = part;
  __syncthreads();
  float mean = (red[0] + red[1] + red[2] + red[3]) * (1.f / CH);
  float d0 = rrow[threadIdx.x] - mean, d1 = rrow[threadIdx.x + 256] - mean;
  float p2 = d0 * d0 + d1 * d1;
  for (int o2 = 32; o2; o2 >>= 1) p2 += __shfl_xor(p2, o2);
  __syncthreads();
  if ((threadIdx.x & 63) == 0) red[(threadIdx.x >> 6) + 4] = p2;
  __syncthreads();
  float rstd = rsqrtf((red[4] + red[5] + red[6] + red[7]) * (1.f / CH) + 1e-5f);
  for (int p = 0; p < 2; ++p) {
    int j = p * 256 + threadIdx.x;
    float xt = (rrow[j] - mean) * rstd * g_lt[j] + b_lt[j];
    atomicAdd(&agg[(size_t)bs * CH + j], xt * (1.f / CT));
  }
}

// ================= launch =================
extern "C" void kernel_launch(void* const* d_in, const int* in_sizes, int n_in,
                              void* d_out, int out_size, void* d_ws, size_t ws_size,
                              hipStream_t stream) {
  (void)in_sizes; (void)n_in; (void)out_size; (void)ws_size;
  const float* visual = (const float*)d_in[0];
  const float* noise  = (const float*)d_in[1];
  const float* mu     = (const float*)d_in[2];
  const float* sigma  = (const float*)d_in[3];
  const float* w_in   = (const float*)d_in[4];
  const float* b_in   = (const float*)d_in[5];
  const float* g_lin  = (const float*)d_in[6];
  const float* b_lin  = (const float*)d_in[7];
  const float* w_m1p  = (const float*)d_in[8];
  const float* b_m1p  = (const float*)d_in[9];
  const float* w_m2p  = (const float*)d_in[10];
  const float* b_m2p  = (const float*)d_in[11];
  const float* w_q    = (const float*)d_in[12];
  const float* w_k    = (const float*)d_in[13];
  const float* w_v    = (const float*)d_in[14];
  const float* w_ih   = (const float*)d_in[15];
  const float* w_hh   = (const float*)d_in[16];
  const float* b_ih   = (const float*)d_in[17];
  const float* b_hh   = (const float*)d_in[18];
  const float* g_ls   = (const float*)d_in[19];
  const float* b_ls   = (const float*)d_in[20];
  const float* g_lm   = (const float*)d_in[21];
  const float* b_lm   = (const float*)d_in[22];
  const float* w_mlp1 = (const float*)d_in[23];
  const float* b_mlp1 = (const float*)d_in[24];
  const float* w_mlp2 = (const float*)d_in[25];
  const float* b_mlp2 = (const float*)d_in[26];
  const float* w_tq   = (const float*)d_in[27];
  const float* b_tq   = (const float*)d_in[28];
  const float* w_tk   = (const float*)d_in[29];
  const float* b_tk   = (const float*)d_in[30];
  const float* w_tv   = (const float*)d_in[31];
  const float* b_tv   = (const float*)d_in[32];
  const float* w_to   = (const float*)d_in[33];
  const float* b_to   = (const float*)d_in[34];
  const float* g_lt   = (const float*)d_in[35];
  const float* b_lt   = (const float*)d_in[36];

  float* ws  = (float*)d_ws;
  float* out = (float*)d_out;
  float* spf = out + 12288;
  float* att = out + 12288 + 196608;

  hipLaunchKernelGGL(k_init, dim3(48), dim3(256), 0, stream, noise, mu, sigma, ws, out);
  hipLaunchKernelGGL(k_transpose, dim3(16, 16, 4), dim3(256), 0, stream,
                     w_to, w_tq, w_tk, w_tv, ws);
  // Stage 1 (BK=16, float4 staging)
  hipLaunchKernelGGL(k_p1, dim3(4, 256), dim3(256), 0, stream,
                     visual, w_in, b_in, ws + OFS_P1);
  hipLaunchKernelGGL(k_rowstats, dim3(CM / 4), dim3(256), 0, stream,
                     ws + OFS_P1, ws + OFS_ST);
  hipLaunchKernelGGL(k_m1, dim3(4, 256), dim3(256), 0, stream,
                     visual, w_m1p, b_m1p, ws + OFS_M1);
  hipLaunchKernelGGL(k_feats, dim3(4, 256), dim3(256), 0, stream,
                     ws + OFS_M1, w_m2p, b_m2p, ws + OFS_ST, g_lin, b_lin, ws + OFS_P1);
  hipLaunchKernelGGL(k_kv, dim3(8, 256), dim3(256), 0, stream,
                     ws + OFS_P1, w_k, w_v, ws + OFS_M1, ws + OFS_V);
  // Stage 2: phase-split scan v3 — read-once weights, 32-128 blocks, short chains
  for (int t = 0; t < CT; ++t) {
    for (int it = 0; it < NITER; ++it) {
      int lastit = (it == NITER - 1) ? 1 : 0;
      hipLaunchKernelGGL(ph_A,  dim3(128),   dim3(256), 0, stream, ws, w_q, w_hh, g_ls, b_ls, b_hh);
      hipLaunchKernelGGL(ph_B1, dim3(8, 8),  dim3(256), 0, stream, ws, att, t, lastit);
      hipLaunchKernelGGL(ph_B2, dim3(2, 24), dim3(256), 0, stream, ws, t);
      hipLaunchKernelGGL(ph_C,  dim3(64),    dim3(256), 0, stream, ws, w_ih, b_ih);
      hipLaunchKernelGGL(ph_D,  dim3(64),    dim3(256), 0, stream, ws, w_mlp1, g_lm, b_lm, b_mlp1);
      hipLaunchKernelGGL(ph_E,  dim3(32),    dim3(256), 0, stream, ws, w_mlp2, b_mlp2, spf, t, lastit);
    }
  }
  // Stage 3: temporal attention
  hipLaunchKernelGGL(k_tproj, dim3(384), dim3(256), 0, stream,
                     spf, ws, b_tq, b_tk, b_tv, ws + OFS_TQKV);
  hipLaunchKernelGGL(k_tattn, dim3(192), dim3(64), 0, stream,
                     ws + OFS_TQKV, ws + OFS_TO);
  hipLaunchKernelGGL(k_tout, dim3(384), dim3(256), 0, stream,
                     ws + OFS_TO, spf, ws, b_to, g_lt, b_lt, out);
}